// Round 3
// baseline (3002.295 us; speedup 1.0000x reference)
//
#include <hip/hip_runtime.h>
#include <hip/hip_bf16.h>

// ---------------------------------------------------------------------------
// Workspace layout (bytes). Peak usage 18,087,936 B — kept small deliberately:
// round-2 evidence indicates writes past ws_size corrupt neighboring
// allocations persistently. All tensors unpadded fp32; convs mask-read OOB.
// ---------------------------------------------------------------------------
static constexpr size_t OFF1_B   = 0;                      // [128,18,16,16]
static constexpr size_t OFF1_SZ  = (size_t)128*18*256*4;   //  2,359,296
static constexpr size_t H1_B     = OFF1_B + OFF1_SZ;       // [128,96,16,16]
static constexpr size_t H1_SZ    = (size_t)128*96*256*4;   // 12,582,912
static constexpr size_t H2POOL_B = H1_B + H1_SZ;           // [128,96,8,8] @14,942,208
static constexpr size_t H2POOL_SZ= (size_t)128*96*64*4;    //  3,145,728  (ends 18,087,936)
// phase 2/3 reuse [0, 14.9M): off1 dead after deform1, h1 dead after conv2pool
static constexpr size_t OFF3_B   = 0;                      // [128,18,8,8]
static constexpr size_t OFF3_SZ  = (size_t)128*18*64*4;    //    589,824
static constexpr size_t H3_B     = OFF3_B + OFF3_SZ;       // [128,108,8,8]
static constexpr size_t H3_SZ    = (size_t)128*108*64*4;   //  3,538,944
static constexpr size_t H4POOL_B = H3_B + H3_SZ;           // [128,108,4,4]
static constexpr size_t H4POOL_SZ= (size_t)128*108*16*4;   //    884,736
static constexpr size_t H5_B     = H4POOL_B + H4POOL_SZ;   // [128,128,4,4]
static constexpr size_t H5_SZ    = (size_t)128*128*16*4;   //  1,048,576
static constexpr size_t H6POOL_B = H5_B + H5_SZ;           // [128,512]
static constexpr size_t H6POOL_SZ= (size_t)128*512*4;      //    262,144
static constexpr size_t FCO_B    = H6POOL_B + H6POOL_SZ;   // [128,200]

// ---------------------------------------------------------------------------
// 3x3 same-conv on unpadded input, masked OOB reads. One thread = one output
// row. Optional BN+ReLU.
// ---------------------------------------------------------------------------
template<int IC, int OC, int H, int W, bool HASBN, bool RELU>
__global__ __launch_bounds__(256) void k_conv3(
    const float* __restrict__ in, const float* __restrict__ w,
    const float* __restrict__ bias,
    const float* __restrict__ bng, const float* __restrict__ bnb,
    const float* __restrict__ bnm, const float* __restrict__ bnv,
    float* __restrict__ out) {
  constexpr int WP = W + 2;
  int t = blockIdx.x * 256 + threadIdx.x;
  if (t >= 128*OC*H) return;
  int h  = t % H;
  int oc = (t / H) % OC;
  int b  = t / (H * OC);
  float acc[W];
#pragma unroll
  for (int i = 0; i < W; ++i) acc[i] = 0.f;
  for (int ci = 0; ci < IC; ++ci) {
    size_t base = ((size_t)b*IC + ci)*(H*W);
    float r[3][WP];
#pragma unroll
    for (int rr = 0; rr < 3; ++rr) {
      int hh = h - 1 + rr;
#pragma unroll
      for (int j = 0; j < WP; ++j) {
        int ww = j - 1;
        bool ok = (hh >= 0) && (hh < H) && (ww >= 0) && (ww < W);
        r[rr][j] = ok ? in[base + hh*W + ww] : 0.f;
      }
    }
    float wv[9];
    size_t wb = ((size_t)oc*IC + ci)*9;
#pragma unroll
    for (int k = 0; k < 9; ++k) wv[k] = w[wb + k];
#pragma unroll
    for (int col = 0; col < W; ++col) {
      float s = acc[col];
#pragma unroll
      for (int i = 0; i < 3; ++i)
#pragma unroll
        for (int j = 0; j < 3; ++j)
          s = fmaf(wv[i*3 + j], r[i][col + j], s);
      acc[col] = s;
    }
  }
  float bi = bias[oc];
  float sc = 1.f, sh = 0.f;
  if (HASBN) {
    float s2 = bng[oc] * rsqrtf(bnv[oc] + 1e-5f);
    sc = s2;
    sh = bnb[oc] - bnm[oc] * s2;
  }
  size_t ob = (((size_t)b*OC + oc)*H + h)*W;
#pragma unroll
  for (int col = 0; col < W; ++col) {
    float val = (acc[col] + bi) * sc + sh;
    if (RELU) val = fmaxf(val, 0.f);
    out[ob + col] = val;
  }
}

// ---------------------------------------------------------------------------
// 3x3 same-conv + bias + BN + ReLU + 2x2 pool (max or avg), fused. One thread
// = one pooled output row (computes 2 conv rows). ReLU applied before avg.
// ---------------------------------------------------------------------------
template<int IC, int OC, int H, int W, bool ISMAX>
__global__ __launch_bounds__(256) void k_convpool(
    const float* __restrict__ in, const float* __restrict__ w,
    const float* __restrict__ bias,
    const float* __restrict__ bng, const float* __restrict__ bnb,
    const float* __restrict__ bnm, const float* __restrict__ bnv,
    float* __restrict__ out) {
  constexpr int WP = W + 2, HO = H/2, WO = W/2;
  int t = blockIdx.x * 256 + threadIdx.x;
  if (t >= 128*OC*HO) return;
  int ho = t % HO;
  int oc = (t / HO) % OC;
  int b  = t / (HO * OC);
  float acc[2][W];
#pragma unroll
  for (int rr = 0; rr < 2; ++rr)
#pragma unroll
    for (int i = 0; i < W; ++i) acc[rr][i] = 0.f;
  for (int ci = 0; ci < IC; ++ci) {
    size_t base = ((size_t)b*IC + ci)*(H*W);
    float r[4][WP];
#pragma unroll
    for (int rr = 0; rr < 4; ++rr) {
      int hh = 2*ho - 1 + rr;
#pragma unroll
      for (int j = 0; j < WP; ++j) {
        int ww = j - 1;
        bool ok = (hh >= 0) && (hh < H) && (ww >= 0) && (ww < W);
        r[rr][j] = ok ? in[base + hh*W + ww] : 0.f;
      }
    }
    float wv[9];
    size_t wb = ((size_t)oc*IC + ci)*9;
#pragma unroll
    for (int k = 0; k < 9; ++k) wv[k] = w[wb + k];
#pragma unroll
    for (int rr = 0; rr < 2; ++rr)
#pragma unroll
      for (int col = 0; col < W; ++col) {
        float s = acc[rr][col];
#pragma unroll
        for (int i = 0; i < 3; ++i)
#pragma unroll
          for (int j = 0; j < 3; ++j)
            s = fmaf(wv[i*3 + j], r[rr + i][col + j], s);
        acc[rr][col] = s;
      }
  }
  float bi = bias[oc];
  float s2 = bng[oc] * rsqrtf(bnv[oc] + 1e-5f);
  float sh = bnb[oc] - bnm[oc] * s2;
  size_t ob = (((size_t)b*OC + oc)*HO + ho)*WO;
#pragma unroll
  for (int wo = 0; wo < WO; ++wo) {
    float a0 = fmaxf((acc[0][2*wo]   + bi) * s2 + sh, 0.f);
    float a1 = fmaxf((acc[0][2*wo+1] + bi) * s2 + sh, 0.f);
    float a2 = fmaxf((acc[1][2*wo]   + bi) * s2 + sh, 0.f);
    float a3 = fmaxf((acc[1][2*wo+1] + bi) * s2 + sh, 0.f);
    out[ob + wo] = ISMAX ? fmaxf(fmaxf(a0, a1), fmaxf(a2, a3))
                         : (a0 + a1 + a2 + a3) * 0.25f;
  }
}

// ---------------------------------------------------------------------------
// Fused deform: bilinear table built in-LDS from offsets (exact reference
// formulas; zero-padding folded: pad-ring corners get weight 0), then gather
// + einsum + BN + ReLU. Block = (b, 64-hw tile). Unpadded input and output.
// ---------------------------------------------------------------------------
template<int IC, int OC, int OCP, int H, int W>
__global__ __launch_bounds__(256) void k_deform(
    const float* __restrict__ in,   // [128,IC,H,W]
    const float* __restrict__ off,  // [128,18,H,W]
    const float* __restrict__ wgt,  // [OC,IC,9]
    const float* __restrict__ bng, const float* __restrict__ bnb,
    const float* __restrict__ bnm, const float* __restrict__ bnv,
    float* __restrict__ out) {     // [128,OC,H,W]
  constexpr int HW = H*W, HP = H + 2, WPD = W + 2;
  constexpr int HWT = 64, CH = 4;
  constexpr int OCA = OCP / 4;
  constexpr int WROW = OCP + 4;
  constexpr int NHWT = HW / HWT;
  __shared__ int4   s_idx[HWT*9];
  __shared__ float4 s_wt[HWT*9];
  __shared__ float  s_v[CH*HWT*9];
  __shared__ __align__(16) float s_w[CH*9*WROW];
  int tid = threadIdx.x;
  int blk = blockIdx.x;
  int b   = blk / NHWT;
  int hw0 = (blk % NHWT) * HWT;
  // build bilinear gather table for this tile
  for (int i = tid; i < HWT*9; i += 256) {
    int lhw = i / 9, n = i % 9;
    int h = (hw0 + lhw) / W, w = (hw0 + lhw) % W;
    float offx = off[(((size_t)b*18 + n)*H + h)*W + w];
    float offy = off[(((size_t)b*18 + 9 + n)*H + h)*W + w];
    float px = (float)(h + n/3) + offx;   // (h+1) + (i-1)
    float py = (float)(w + n%3) + offy;   // (w+1) + (j-1)
    px = fminf(fmaxf(px, 0.f), (float)(HP - 1));
    py = fminf(fmaxf(py, 0.f), (float)(WPD - 1));
    float x0 = floorf(px), y0 = floorf(py);
    float x1 = fminf(x0 + 1.f, (float)(HP - 1));
    float y1 = fminf(y0 + 1.f, (float)(WPD - 1));
    float glt = (1.f + x0 - px) * (1.f + y0 - py);
    float grb = (1.f - x1 + px) * (1.f - y1 + py);
    float glb = (1.f + x0 - px) * (1.f - y1 + py);
    float grt = (1.f - x1 + px) * (1.f + y0 - py);
    int   cx[4] = {(int)x0, (int)x1, (int)x0, (int)x1};
    int   cy[4] = {(int)y0, (int)y1, (int)y1, (int)y0};
    float gw[4] = {glt, grb, glb, grt};
    int   id[4]; float gg[4];
#pragma unroll
    for (int c = 0; c < 4; ++c) {
      bool ok = (cx[c] >= 1) && (cx[c] <= H) && (cy[c] >= 1) && (cy[c] <= W);
      id[c] = ok ? ((cx[c]-1)*W + (cy[c]-1)) : 0;
      gg[c] = ok ? gw[c] : 0.f;
    }
    s_idx[i] = make_int4(id[0], id[1], id[2], id[3]);
    s_wt[i]  = make_float4(gg[0], gg[1], gg[2], gg[3]);
  }
  __syncthreads();
  int hwi = tid & 63;
  int og  = tid >> 6;
  float acc[OCA];
#pragma unroll
  for (int o = 0; o < OCA; ++o) acc[o] = 0.f;
  for (int cc = 0; cc < IC; cc += CH) {
    for (int i2 = tid; i2 < OCP*CH*9; i2 += 256) {
      int oc = i2 / (CH*9);
      int k  = i2 % (CH*9);
      float val = 0.f;
      if (oc < OC) {
        int ci = k / 9, n = k % 9;
        val = wgt[((size_t)oc*IC + cc + ci)*9 + n];
      }
      s_w[k*WROW + oc] = val;
    }
    for (int i2 = tid; i2 < CH*HWT*9; i2 += 256) {
      int ci = i2 / (HWT*9);
      int r  = i2 % (HWT*9);
      int4   t4 = s_idx[r];
      float4 w4 = s_wt[r];
      const float* pb = in + ((size_t)b*IC + cc + ci)*HW;
      s_v[i2] = w4.x*pb[t4.x] + w4.y*pb[t4.y] + w4.z*pb[t4.z] + w4.w*pb[t4.w];
    }
    __syncthreads();
#pragma unroll
    for (int ci = 0; ci < CH; ++ci) {
#pragma unroll
      for (int n = 0; n < 9; ++n) {
        float v = s_v[ci*HWT*9 + hwi*9 + n];
        const float4* wr = (const float4*)&s_w[(ci*9 + n)*WROW + og*OCA];
#pragma unroll
        for (int o = 0; o < OCA/4; ++o) {
          float4 w4 = wr[o];
          acc[4*o]   = fmaf(v, w4.x, acc[4*o]);
          acc[4*o+1] = fmaf(v, w4.y, acc[4*o+1]);
          acc[4*o+2] = fmaf(v, w4.z, acc[4*o+2]);
          acc[4*o+3] = fmaf(v, w4.w, acc[4*o+3]);
        }
      }
    }
    __syncthreads();
  }
  int hw = hw0 + hwi;
#pragma unroll
  for (int o = 0; o < OCA; ++o) {
    int oc = og*OCA + o;
    if (oc < OC) {
      float sc = bng[oc] * rsqrtf(bnv[oc] + 1e-5f);
      float val = fmaxf(acc[o]*sc + (bnb[oc] - bnm[oc]*sc), 0.f);
      out[((size_t)b*OC + oc)*HW + hw] = val;
    }
  }
}

__global__ __launch_bounds__(256) void k_fc(const float* __restrict__ in,
                                            const float* __restrict__ w,
                                            const float* __restrict__ bias,
                                            float* __restrict__ out) {
  int t = blockIdx.x * 256 + threadIdx.x;
  if (t >= 128*200) return;
  int j = t % 200, b = t / 200;
  float acc = bias[j];
  const float* ib = in + (size_t)b*512;
  const float* wb = w + (size_t)j*512;
  for (int k = 0; k < 512; ++k) acc = fmaf(ib[k], wb[k], acc);
  out[t] = acc;
}

__global__ __launch_bounds__(256) void k_fc1(const float* __restrict__ in,
                                             const float* __restrict__ w,
                                             const float* __restrict__ bias,
                                             float* __restrict__ out) {
  int t = blockIdx.x * 256 + threadIdx.x;
  if (t >= 128*16) return;
  int j = t % 16, b = t / 16;
  float acc = bias[j];
  const float* ib = in + (size_t)b*200;
  const float* wb = w + (size_t)j*200;
  for (int k = 0; k < 200; ++k) acc = fmaf(ib[k], wb[k], acc);
  out[t] = acc;
}

// ---------------------------------------------------------------------------
extern "C" void kernel_launch(void* const* d_in, const int* in_sizes, int n_in,
                              void* d_out, int out_size, void* d_ws, size_t ws_size,
                              hipStream_t stream) {
  const float* X     = (const float*)d_in[0];
  const float* D1PW  = (const float*)d_in[1];
  const float* D1PB  = (const float*)d_in[2];
  const float* D1W   = (const float*)d_in[3];
  const float* BN1G  = (const float*)d_in[4];
  const float* BN1B  = (const float*)d_in[5];
  const float* BN1M  = (const float*)d_in[6];
  const float* BN1V  = (const float*)d_in[7];
  const float* C2W   = (const float*)d_in[8];
  const float* C2B   = (const float*)d_in[9];
  const float* BN2G  = (const float*)d_in[10];
  const float* BN2B  = (const float*)d_in[11];
  const float* BN2M  = (const float*)d_in[12];
  const float* BN2V  = (const float*)d_in[13];
  const float* D3PW  = (const float*)d_in[14];
  const float* D3PB  = (const float*)d_in[15];
  const float* D3W   = (const float*)d_in[16];
  const float* BN3G  = (const float*)d_in[17];
  const float* BN3B  = (const float*)d_in[18];
  const float* BN3M  = (const float*)d_in[19];
  const float* BN3V  = (const float*)d_in[20];
  const float* C4W   = (const float*)d_in[21];
  const float* C4B   = (const float*)d_in[22];
  const float* BN4G  = (const float*)d_in[23];
  const float* BN4B  = (const float*)d_in[24];
  const float* BN4M  = (const float*)d_in[25];
  const float* BN4V  = (const float*)d_in[26];
  const float* C5W   = (const float*)d_in[27];
  const float* C5B   = (const float*)d_in[28];
  const float* BN5G  = (const float*)d_in[29];
  const float* BN5B  = (const float*)d_in[30];
  const float* BN5M  = (const float*)d_in[31];
  const float* BN5V  = (const float*)d_in[32];
  const float* C6W   = (const float*)d_in[33];
  const float* C6B   = (const float*)d_in[34];
  const float* BN6G  = (const float*)d_in[35];
  const float* BN6B  = (const float*)d_in[36];
  const float* BN6M  = (const float*)d_in[37];
  const float* BN6V  = (const float*)d_in[38];
  const float* FCW   = (const float*)d_in[39];
  const float* FCB   = (const float*)d_in[40];
  const float* FC1W  = (const float*)d_in[41];
  const float* FC1B  = (const float*)d_in[42];

  char* ws = (char*)d_ws;
  float* off1   = (float*)(ws + OFF1_B);
  float* h1     = (float*)(ws + H1_B);
  float* h2pool = (float*)(ws + H2POOL_B);
  float* off3   = (float*)(ws + OFF3_B);
  float* h3     = (float*)(ws + H3_B);
  float* h4pool = (float*)(ws + H4POOL_B);
  float* h5     = (float*)(ws + H5_B);
  float* h6pool = (float*)(ws + H6POOL_B);
  float* fco    = (float*)(ws + FCO_B);
  float* outp   = (float*)d_out;

  // block 1: deform conv (offset conv -> fused deform einsum)
  k_conv3<200,18,16,16,false,false><<<144, 256, 0, stream>>>(
      X, D1PW, D1PB, nullptr, nullptr, nullptr, nullptr, off1);
  k_deform<200,96,96,16,16><<<512, 256, 0, stream>>>(
      X, off1, D1W, BN1G, BN1B, BN1M, BN1V, h1);
  // block 2: conv + BN + ReLU + maxpool (fused)
  k_convpool<96,96,16,16,true><<<384, 256, 0, stream>>>(
      h1, C2W, C2B, BN2G, BN2B, BN2M, BN2V, h2pool);
  // block 3: deform conv
  k_conv3<96,18,8,8,false,false><<<72, 256, 0, stream>>>(
      h2pool, D3PW, D3PB, nullptr, nullptr, nullptr, nullptr, off3);
  k_deform<96,108,112,8,8><<<128, 256, 0, stream>>>(
      h2pool, off3, D3W, BN3G, BN3B, BN3M, BN3V, h3);
  // block 4: conv + BN + ReLU + maxpool (fused)
  k_convpool<108,108,8,8,true><<<216, 256, 0, stream>>>(
      h3, C4W, C4B, BN4G, BN4B, BN4M, BN4V, h4pool);
  // block 5: conv + BN + ReLU
  k_conv3<108,128,4,4,true,true><<<256, 256, 0, stream>>>(
      h4pool, C5W, C5B, BN5G, BN5B, BN5M, BN5V, h5);
  // block 6: conv + BN + ReLU + avgpool (fused, ReLU before avg)
  k_convpool<128,128,4,4,false><<<128, 256, 0, stream>>>(
      h5, C6W, C6B, BN6G, BN6B, BN6M, BN6V, h6pool);
  // classifier
  k_fc<<<100, 256, 0, stream>>>(h6pool, FCW, FCB, fco);
  k_fc1<<<8, 256, 0, stream>>>(fco, FC1W, FC1B, outp);
}

// Round 4
// 1704.615 us; speedup vs baseline: 1.7613x; 1.7613x over previous
//
#include <hip/hip_runtime.h>

// ---------------------------------------------------------------------------
// Workspace layout (bytes). Peak 18,087,936 B (== round-3 peak, known safe).
// ---------------------------------------------------------------------------
static constexpr size_t OFF1_B = 0;               // [128,18,16,16] 2,359,296
static constexpr size_t H1_B   = 2359296;         // [128,96,16,16] 12,582,912
static constexpr size_t H2P_B  = 14942208;        // [128,96,8,8]   3,145,728 (ends 18,087,936)
// off1/h1 dead after conv2 -> reuse [0, 14.9M)
static constexpr size_t OFF3_B = 0;               // [128,18,8,8]     589,824
static constexpr size_t H3_B   = 589824;          // [128,108,8,8]  3,538,944
static constexpr size_t H4P_B  = 4128768;         // [128,108,4,4]    884,736
static constexpr size_t H5_B   = 5013504;         // [128,128,4,4]  1,048,576
static constexpr size_t H6P_B  = 6062080;         // [128,512]        262,144
static constexpr size_t FCO_B  = 6324224;         // [128,200]        102,400

// ---------------------------------------------------------------------------
// Tiled 3x3 same-conv. Block = (batch, row-tile); 256 threads = (pixel, ocg).
// Input tile staged in LDS with halo; weights staged in LDS, read as
// wave-broadcast float4. POOL: 0 none, 1 max2x2, 2 avg2x2 (ReLU before avg),
// pooling done in-register via __shfl_xor (wave64 holds the 2x2 neighbors).
// ---------------------------------------------------------------------------
template<int IC, int OC, int OCW, int H, int W, bool HASBN, bool RELU, int POOL>
__global__ __launch_bounds__(256) void k_conv(
    const float* __restrict__ in, const float* __restrict__ w,
    const float* __restrict__ bias,
    const float* __restrict__ bng, const float* __restrict__ bnb,
    const float* __restrict__ bnm, const float* __restrict__ bnv,
    float* __restrict__ out) {
  constexpr int HW    = H * W;
  constexpr int TPIX  = (HW < 64) ? HW : 64;
  constexpr int TILES = HW / TPIX;
  constexpr int NGRP  = 256 / TPIX;
  constexpr int OCA   = OCW / NGRP;
  constexpr int RT    = TPIX / W;
  constexpr int WP    = W + 2;
  constexpr int CH    = 4;
  constexpr int RROWS = RT + 2;
  constexpr int SIN   = CH * RROWS * WP;
  __shared__ float s_in[SIN];
  __shared__ __align__(16) float s_w[CH * 9 * OCW];
  const int tid = threadIdx.x;
  const int b   = blockIdx.x / TILES;
  const int r0  = (blockIdx.x % TILES) * RT;
  const int pix = tid % TPIX;
  const int ocg = tid / TPIX;
  const int r = pix / W, c = pix % W;
  float acc[OCA];
#pragma unroll
  for (int o = 0; o < OCA; ++o) acc[o] = 0.f;

  for (int cc = 0; cc < IC; cc += CH) {
    __syncthreads();
    for (int i = tid; i < SIN; i += 256) {
      int ci  = i / (RROWS * WP);
      int rem = i % (RROWS * WP);
      int rr  = rem / WP + r0 - 1;
      int cw  = rem % WP - 1;
      bool ok = (rr >= 0) && (rr < H) && (cw >= 0) && (cw < W);
      s_in[i] = ok ? in[(((size_t)b*IC + cc + ci)*H + rr)*W + cw] : 0.f;
    }
    for (int i = tid; i < CH * 9 * OCW; i += 256) {
      int oc = i % OCW, k = i / OCW;
      s_w[i] = (oc < OC) ? w[((size_t)oc*IC + cc + (k/9))*9 + (k%9)] : 0.f;
    }
    __syncthreads();
#pragma unroll
    for (int ci = 0; ci < CH; ++ci) {
      const float* sp = s_in + ci*RROWS*WP + r*WP + c;
#pragma unroll
      for (int n = 0; n < 9; ++n) {
        float v = sp[(n/3)*WP + (n%3)];
        const float* wr = s_w + (ci*9 + n)*OCW + ocg*OCA;
        if constexpr ((OCA & 3) == 0) {
          const float4* w4 = (const float4*)wr;
#pragma unroll
          for (int o = 0; o < OCA/4; ++o) {
            float4 ww = w4[o];
            acc[4*o  ] = fmaf(v, ww.x, acc[4*o  ]);
            acc[4*o+1] = fmaf(v, ww.y, acc[4*o+1]);
            acc[4*o+2] = fmaf(v, ww.z, acc[4*o+2]);
            acc[4*o+3] = fmaf(v, ww.w, acc[4*o+3]);
          }
        } else {
#pragma unroll
          for (int o = 0; o < OCA; ++o)
            acc[o] = fmaf(v, wr[o], acc[o]);
        }
      }
    }
  }
  // epilogue: bias (+BN) (+ReLU) (+pool via wave shuffles)
#pragma unroll
  for (int o = 0; o < OCA; ++o) {
    int oc = ocg*OCA + o;
    float e = 0.f;
    if (oc < OC) {
      e = acc[o] + bias[oc];
      if constexpr (HASBN) {
        float sc = bng[oc] * rsqrtf(bnv[oc] + 1e-5f);
        e = e * sc + (bnb[oc] - bnm[oc]*sc);
      }
      if constexpr (RELU) e = fmaxf(e, 0.f);
    }
    if constexpr (POOL == 0) {
      if (oc < OC)
        out[(((size_t)b*OC + oc)*H + (r0 + r))*W + c] = e;
    } else {
      float e1 = __shfl_xor(e, 1);
      float e2 = __shfl_xor(e, W);
      float e3 = __shfl_xor(e, W + 1);
      float m = (POOL == 1) ? fmaxf(fmaxf(e, e1), fmaxf(e2, e3))
                            : (e + e1 + e2 + e3) * 0.25f;
      if (oc < OC && !(r & 1) && !(c & 1))
        out[(((size_t)b*OC + oc)*(H/2) + (r0 + r)/2)*(W/2) + (c/2)] = m;
    }
  }
}

// ---------------------------------------------------------------------------
// Fused deform conv: bilinear table built in-LDS (exact reference formulas,
// zero-padding folded: pad-ring corners get weight 0), gather into LDS,
// einsum with LDS weight tile (broadcast float4), BN+ReLU epilogue.
// Block = (batch, 64-pixel tile); 256 threads = (pixel, ocg of 4).
// ---------------------------------------------------------------------------
template<int IC, int OC, int OCW, int H, int W>
__global__ __launch_bounds__(256) void k_deform(
    const float* __restrict__ in,   // [128,IC,H,W]
    const float* __restrict__ off,  // [128,18,H,W]
    const float* __restrict__ wgt,  // [OC,IC,9]
    const float* __restrict__ bng, const float* __restrict__ bnb,
    const float* __restrict__ bnm, const float* __restrict__ bnv,
    float* __restrict__ out) {      // [128,OC,H,W]
  constexpr int HW = H*W, HP = H + 2, WPD = W + 2;
  constexpr int TILES = HW / 64;
  constexpr int CH = 4;
  constexpr int OCA = OCW / 4;
  __shared__ int4   s_idx[576];
  __shared__ float4 s_wt[576];
  __shared__ float  s_v[CH * 576];
  __shared__ __align__(16) float s_w[CH * 9 * OCW];
  const int tid = threadIdx.x;
  const int b   = blockIdx.x / TILES;
  const int hw0 = (blockIdx.x % TILES) * 64;
  // build bilinear gather table for this tile
  for (int i = tid; i < 576; i += 256) {
    int lhw = i / 9, n = i % 9;
    int h = (hw0 + lhw) / W, w = (hw0 + lhw) % W;
    float offx = off[(((size_t)b*18 + n)*H + h)*W + w];
    float offy = off[(((size_t)b*18 + 9 + n)*H + h)*W + w];
    float px = (float)(h + n/3) + offx;
    float py = (float)(w + n%3) + offy;
    px = fminf(fmaxf(px, 0.f), (float)(HP - 1));
    py = fminf(fmaxf(py, 0.f), (float)(WPD - 1));
    float x0 = floorf(px), y0 = floorf(py);
    float x1 = fminf(x0 + 1.f, (float)(HP - 1));
    float y1 = fminf(y0 + 1.f, (float)(WPD - 1));
    float glt = (1.f + x0 - px) * (1.f + y0 - py);
    float grb = (1.f - x1 + px) * (1.f - y1 + py);
    float glb = (1.f + x0 - px) * (1.f - y1 + py);
    float grt = (1.f - x1 + px) * (1.f + y0 - py);
    int   cx[4] = {(int)x0, (int)x1, (int)x0, (int)x1};
    int   cy[4] = {(int)y0, (int)y1, (int)y1, (int)y0};
    float gw[4] = {glt, grb, glb, grt};
    int id[4]; float gg[4];
#pragma unroll
    for (int q = 0; q < 4; ++q) {
      bool ok = (cx[q] >= 1) && (cx[q] <= H) && (cy[q] >= 1) && (cy[q] <= W);
      id[q] = ok ? ((cx[q]-1)*W + (cy[q]-1)) : 0;
      gg[q] = ok ? gw[q] : 0.f;
    }
    s_idx[i] = make_int4(id[0], id[1], id[2], id[3]);
    s_wt[i]  = make_float4(gg[0], gg[1], gg[2], gg[3]);
  }
  __syncthreads();
  const int hwi = tid & 63;
  const int ocg = tid >> 6;
  float acc[OCA];
#pragma unroll
  for (int o = 0; o < OCA; ++o) acc[o] = 0.f;
  for (int cc = 0; cc < IC; cc += CH) {
    for (int i = tid; i < CH * 9 * OCW; i += 256) {
      int oc = i % OCW, k = i / OCW;
      s_w[i] = (oc < OC) ? wgt[((size_t)oc*IC + cc + (k/9))*9 + (k%9)] : 0.f;
    }
    for (int i = tid; i < CH * 576; i += 256) {
      int ci = i / 576, rr = i % 576;
      int4   t4 = s_idx[rr];
      float4 w4 = s_wt[rr];
      const float* pb = in + ((size_t)b*IC + cc + ci)*HW;
      s_v[i] = w4.x*pb[t4.x] + w4.y*pb[t4.y] + w4.z*pb[t4.z] + w4.w*pb[t4.w];
    }
    __syncthreads();
#pragma unroll
    for (int ci = 0; ci < CH; ++ci) {
#pragma unroll
      for (int n = 0; n < 9; ++n) {
        float v = s_v[ci*576 + hwi*9 + n];
        const float4* w4 = (const float4*)(s_w + (ci*9 + n)*OCW + ocg*OCA);
#pragma unroll
        for (int o = 0; o < OCA/4; ++o) {
          float4 ww = w4[o];
          acc[4*o  ] = fmaf(v, ww.x, acc[4*o  ]);
          acc[4*o+1] = fmaf(v, ww.y, acc[4*o+1]);
          acc[4*o+2] = fmaf(v, ww.z, acc[4*o+2]);
          acc[4*o+3] = fmaf(v, ww.w, acc[4*o+3]);
        }
      }
    }
    __syncthreads();
  }
#pragma unroll
  for (int o = 0; o < OCA; ++o) {
    int oc = ocg*OCA + o;
    if (oc < OC) {
      float sc = bng[oc] * rsqrtf(bnv[oc] + 1e-5f);
      float val = fmaxf(acc[o]*sc + (bnb[oc] - bnm[oc]*sc), 0.f);
      out[((size_t)b*OC + oc)*HW + hw0 + hwi] = val;
    }
  }
}

// FC: block = output row j (weight addresses block-uniform -> scalar loads),
// thread = batch b.
__global__ __launch_bounds__(128) void k_fc(const float* __restrict__ in,
                                            const float* __restrict__ w,
                                            const float* __restrict__ bias,
                                            float* __restrict__ out) {
  int j = blockIdx.x, b = threadIdx.x;
  const float4* ib = (const float4*)(in + (size_t)b*512);
  const float4* wb = (const float4*)(w + (size_t)j*512);
  float acc = bias[j];
  for (int k = 0; k < 128; ++k) {
    float4 a = ib[k], q = wb[k];
    acc = fmaf(a.x, q.x, fmaf(a.y, q.y, fmaf(a.z, q.z, fmaf(a.w, q.w, acc))));
  }
  out[(size_t)b*200 + j] = acc;
}

__global__ __launch_bounds__(128) void k_fc1(const float* __restrict__ in,
                                             const float* __restrict__ w,
                                             const float* __restrict__ bias,
                                             float* __restrict__ out) {
  int j = blockIdx.x, b = threadIdx.x;
  const float4* ib = (const float4*)(in + (size_t)b*200);
  const float4* wb = (const float4*)(w + (size_t)j*200);
  float acc = bias[j];
  for (int k = 0; k < 50; ++k) {
    float4 a = ib[k], q = wb[k];
    acc = fmaf(a.x, q.x, fmaf(a.y, q.y, fmaf(a.z, q.z, fmaf(a.w, q.w, acc))));
  }
  out[(size_t)b*16 + j] = acc;
}

// ---------------------------------------------------------------------------
extern "C" void kernel_launch(void* const* d_in, const int* in_sizes, int n_in,
                              void* d_out, int out_size, void* d_ws, size_t ws_size,
                              hipStream_t stream) {
  const float* X    = (const float*)d_in[0];
  const float* D1PW = (const float*)d_in[1];
  const float* D1PB = (const float*)d_in[2];
  const float* D1W  = (const float*)d_in[3];
  const float* BN1G = (const float*)d_in[4];
  const float* BN1B = (const float*)d_in[5];
  const float* BN1M = (const float*)d_in[6];
  const float* BN1V = (const float*)d_in[7];
  const float* C2W  = (const float*)d_in[8];
  const float* C2B  = (const float*)d_in[9];
  const float* BN2G = (const float*)d_in[10];
  const float* BN2B = (const float*)d_in[11];
  const float* BN2M = (const float*)d_in[12];
  const float* BN2V = (const float*)d_in[13];
  const float* D3PW = (const float*)d_in[14];
  const float* D3PB = (const float*)d_in[15];
  const float* D3W  = (const float*)d_in[16];
  const float* BN3G = (const float*)d_in[17];
  const float* BN3B = (const float*)d_in[18];
  const float* BN3M = (const float*)d_in[19];
  const float* BN3V = (const float*)d_in[20];
  const float* C4W  = (const float*)d_in[21];
  const float* C4B  = (const float*)d_in[22];
  const float* BN4G = (const float*)d_in[23];
  const float* BN4B = (const float*)d_in[24];
  const float* BN4M = (const float*)d_in[25];
  const float* BN4V = (const float*)d_in[26];
  const float* C5W  = (const float*)d_in[27];
  const float* C5B  = (const float*)d_in[28];
  const float* BN5G = (const float*)d_in[29];
  const float* BN5B = (const float*)d_in[30];
  const float* BN5M = (const float*)d_in[31];
  const float* BN5V = (const float*)d_in[32];
  const float* C6W  = (const float*)d_in[33];
  const float* C6B  = (const float*)d_in[34];
  const float* BN6G = (const float*)d_in[35];
  const float* BN6B = (const float*)d_in[36];
  const float* BN6M = (const float*)d_in[37];
  const float* BN6V = (const float*)d_in[38];
  const float* FCW  = (const float*)d_in[39];
  const float* FCB  = (const float*)d_in[40];
  const float* FC1W = (const float*)d_in[41];
  const float* FC1B = (const float*)d_in[42];

  char* ws = (char*)d_ws;
  float* off1 = (float*)(ws + OFF1_B);
  float* h1   = (float*)(ws + H1_B);
  float* h2p  = (float*)(ws + H2P_B);
  float* off3 = (float*)(ws + OFF3_B);
  float* h3   = (float*)(ws + H3_B);
  float* h4p  = (float*)(ws + H4P_B);
  float* h5   = (float*)(ws + H5_B);
  float* h6p  = (float*)(ws + H6P_B);
  float* fco  = (float*)(ws + FCO_B);
  float* outp = (float*)d_out;

  // block 1: deform conv (offset conv -> fused deform einsum)
  k_conv<200,18,20,16,16,false,false,0><<<512, 256, 0, stream>>>(
      X, D1PW, D1PB, nullptr, nullptr, nullptr, nullptr, off1);
  k_deform<200,96,96,16,16><<<512, 256, 0, stream>>>(
      X, off1, D1W, BN1G, BN1B, BN1M, BN1V, h1);
  // block 2: conv + BN + ReLU + maxpool
  k_conv<96,96,96,16,16,true,true,1><<<512, 256, 0, stream>>>(
      h1, C2W, C2B, BN2G, BN2B, BN2M, BN2V, h2p);
  // block 3: deform conv
  k_conv<96,18,20,8,8,false,false,0><<<128, 256, 0, stream>>>(
      h2p, D3PW, D3PB, nullptr, nullptr, nullptr, nullptr, off3);
  k_deform<96,108,112,8,8><<<128, 256, 0, stream>>>(
      h2p, off3, D3W, BN3G, BN3B, BN3M, BN3V, h3);
  // block 4: conv + BN + ReLU + maxpool
  k_conv<108,108,112,8,8,true,true,1><<<128, 256, 0, stream>>>(
      h3, C4W, C4B, BN4G, BN4B, BN4M, BN4V, h4p);
  // block 5: conv + BN + ReLU
  k_conv<108,128,128,4,4,true,true,0><<<128, 256, 0, stream>>>(
      h4p, C5W, C5B, BN5G, BN5B, BN5M, BN5V, h5);
  // block 6: conv + BN + ReLU + avgpool (ReLU before avg)
  k_conv<128,128,128,4,4,true,true,2><<<128, 256, 0, stream>>>(
      h5, C6W, C6B, BN6G, BN6B, BN6M, BN6V, h6p);
  // classifier
  k_fc<<<200, 128, 0, stream>>>(h6p, FCW, FCB, fco);
  k_fc1<<<16, 128, 0, stream>>>(fco, FC1W, FC1B, outp);
}

// Round 5
// 1507.446 us; speedup vs baseline: 1.9916x; 1.1308x over previous
//
#include <hip/hip_runtime.h>

typedef __attribute__((ext_vector_type(8))) short short8;
typedef __attribute__((ext_vector_type(4))) float f32x4;

#define MFMA16(a, b, c) __builtin_amdgcn_mfma_f32_16x16x32_bf16(a, b, c, 0, 0, 0)

__device__ __forceinline__ unsigned short f2bf(float x) {
  union { float f; unsigned u; } c; c.f = x;
  unsigned r = c.u + 0x7FFFu + ((c.u >> 16) & 1u);
  return (unsigned short)(r >> 16);
}
__device__ __forceinline__ float bf2f(unsigned short h) {
  union { unsigned u; float f; } c; c.u = ((unsigned)h) << 16; return c.f;
}

// ---------------------------------------------------------------------------
// Workspace layout (bytes). Peak 18,087,936 B (round-3/4 proven safe).
// ---------------------------------------------------------------------------
static constexpr size_t OFF1_B = 0;               // [128,18,16,16] 2,359,296
static constexpr size_t H1_B   = 2359296;         // [128,96,16,16] 12,582,912
static constexpr size_t H2P_B  = 14942208;        // [128,96,8,8]   3,145,728
static constexpr size_t OFF3_B = 0;               // [128,18,8,8]     589,824
static constexpr size_t H3_B   = 589824;          // [128,108,8,8]  3,538,944
static constexpr size_t H4P_B  = 4128768;         // [128,108,4,4]    884,736
static constexpr size_t H5_B   = 5013504;         // [128,128,4,4]  1,048,576
static constexpr size_t H6P_B  = 6062080;         // [128,512]        262,144
static constexpr size_t FCO_B  = 6324224;         // [128,200]        102,400

// ---------------------------------------------------------------------------
// MFMA implicit-GEMM conv / deform-conv, split-bf16 x3 for fp32 accuracy.
// Block = (batch, 64-pixel tile). A = im2col/gathered input [64 x K],
// B = weights [K x OC] (global layout [OC][K] is k-contig -> staged as B^T).
// K panels of 64; per panel 2 MFMA k-steps of 32; D = AhBh + AlBh + AhBl.
// Epilogues: +bias / BN+ReLU / BN+ReLU+maxpool2x2 (via LDS bounce).
// ---------------------------------------------------------------------------
template<bool GATHER, int IC, int OC, int OCPAD, int NTILES, int H, int W,
         bool HASBIAS, bool HASBN, bool RELU, bool POOLMAX>
__global__ __launch_bounds__(256) void k_gemm(
    const float* __restrict__ in,   // [128,IC,H,W]
    const float* __restrict__ off,  // [128,18,H,W] (GATHER only)
    const float* __restrict__ wgt,  // [OC, IC*9]
    const float* __restrict__ bias,
    const float* __restrict__ bng, const float* __restrict__ bnb,
    const float* __restrict__ bnm, const float* __restrict__ bnv,
    float* __restrict__ out) {
  static_assert(!(GATHER && POOLMAX), "s_out aliases gather tables");
  constexpr int HW     = H * W;
  constexpr int K      = IC * 9;
  constexpr int NPANEL = (K + 63) / 64;
  constexpr int TILES  = HW / 64;
  constexpr int HP = H + 2, WPD = W + 2;
  constexpr int SAS    = 72;                    // u16 per LDS row (64 + pad 8)
  constexpr int ASZ    = 64 * SAS * 2;          // 9216 B per A buffer
  constexpr int BSZ    = OCPAD * SAS * 2;
  constexpr int IDXSZ  = GATHER ? 576 * 24 : 0; // ushort4 idx + float4 wt
  constexpr int OCS    = OC + 1;
  constexpr int PBYTES = IDXSZ + 2 * ASZ + 2 * BSZ;
  __shared__ __align__(16) char pool[PBYTES];
  ushort4* s_idx = (ushort4*)pool;                      // GATHER only
  float4*  s_wt  = (float4*)(pool + 576 * 8);           // GATHER only
  unsigned short* s_ah = (unsigned short*)(pool + IDXSZ);
  unsigned short* s_al = (unsigned short*)(pool + IDXSZ + ASZ);
  unsigned short* s_bh = (unsigned short*)(pool + IDXSZ + 2 * ASZ);
  unsigned short* s_bl = (unsigned short*)(pool + IDXSZ + 2 * ASZ + BSZ);
  float* s_out = (float*)pool;                          // POOLMAX only (aliases)

  const int tid = threadIdx.x;
  const int b   = blockIdx.x / TILES;
  const int hw0 = (blockIdx.x % TILES) * 64;

  if constexpr (GATHER) {
    // bilinear gather table, exact reference formulas; zero-padding folded
    for (int i = tid; i < 576; i += 256) {
      int px = i / 9, n = i % 9;
      int h = (hw0 + px) / W, w = (hw0 + px) % W;
      float offx = off[(((size_t)b*18 + n)*H + h)*W + w];
      float offy = off[(((size_t)b*18 + 9 + n)*H + h)*W + w];
      float pxv = (float)(h + n/3) + offx;
      float pyv = (float)(w + n%3) + offy;
      pxv = fminf(fmaxf(pxv, 0.f), (float)(HP - 1));
      pyv = fminf(fmaxf(pyv, 0.f), (float)(WPD - 1));
      float x0 = floorf(pxv), y0 = floorf(pyv);
      float x1 = fminf(x0 + 1.f, (float)(HP - 1));
      float y1 = fminf(y0 + 1.f, (float)(WPD - 1));
      float glt = (1.f + x0 - pxv) * (1.f + y0 - pyv);
      float grb = (1.f - x1 + pxv) * (1.f - y1 + pyv);
      float glb = (1.f + x0 - pxv) * (1.f - y1 + pyv);
      float grt = (1.f - x1 + pxv) * (1.f + y0 - pyv);
      int   cx[4] = {(int)x0, (int)x1, (int)x0, (int)x1};
      int   cy[4] = {(int)y0, (int)y1, (int)y1, (int)y0};
      float gw[4] = {glt, grb, glb, grt};
      unsigned short id[4]; float gg[4];
#pragma unroll
      for (int q = 0; q < 4; ++q) {
        bool ok = (cx[q] >= 1) && (cx[q] <= H) && (cy[q] >= 1) && (cy[q] <= W);
        id[q] = ok ? (unsigned short)((cx[q]-1)*W + (cy[q]-1)) : (unsigned short)0;
        gg[q] = ok ? gw[q] : 0.f;
      }
      s_idx[i] = make_ushort4(id[0], id[1], id[2], id[3]);
      s_wt[i]  = make_float4(gg[0], gg[1], gg[2], gg[3]);
    }
  }
  __syncthreads();

  const int lane = tid & 63;
  const int wv   = tid >> 6;
  const int m16  = lane & 15;
  const int quad = lane >> 4;
  f32x4 acc[NTILES];
#pragma unroll
  for (int nt = 0; nt < NTILES; ++nt) acc[nt] = (f32x4){0.f, 0.f, 0.f, 0.f};

  for (int p = 0; p < NPANEL; ++p) {
    const int k0 = p * 64;
    __syncthreads();
    // stage A [64 px x 64 k] as bf16 hi/lo
    for (int e = tid; e < 64 * 64; e += 256) {
      int px = e >> 6, kk = e & 63, k = k0 + kk;
      float v = 0.f;
      if (k < K) {
        int ci = k / 9, n = k - ci * 9;
        if constexpr (GATHER) {
          ushort4 t4 = s_idx[px*9 + n];
          float4  w4 = s_wt[px*9 + n];
          const float* pb = in + ((size_t)b*IC + ci)*HW;
          v = w4.x*pb[t4.x] + w4.y*pb[t4.y] + w4.z*pb[t4.z] + w4.w*pb[t4.w];
        } else {
          int hw = hw0 + px, r = hw / W, c = hw % W;
          int rr = r + n/3 - 1, cc = c + n%3 - 1;
          if (rr >= 0 && rr < H && cc >= 0 && cc < W)
            v = in[((size_t)b*IC + ci)*HW + rr*W + cc];
        }
      }
      unsigned short hb = f2bf(v);
      s_ah[px*SAS + kk] = hb;
      s_al[px*SAS + kk] = f2bf(v - bf2f(hb));
    }
    // stage B^T [OCPAD x 64 k] (wgt rows are k-contig)
    for (int e = tid; e < OCPAD * 64; e += 256) {
      int oc = e >> 6, kk = e & 63, k = k0 + kk;
      float v = (oc < OC && k < K) ? wgt[(size_t)oc*K + k] : 0.f;
      unsigned short hb = f2bf(v);
      s_bh[oc*SAS + kk] = hb;
      s_bl[oc*SAS + kk] = f2bf(v - bf2f(hb));
    }
    __syncthreads();
#pragma unroll
    for (int ks = 0; ks < 2; ++ks) {
      const int ko = ks*32 + quad*8;
      short8 ah = *(const short8*)&s_ah[(wv*16 + m16)*SAS + ko];
      short8 al = *(const short8*)&s_al[(wv*16 + m16)*SAS + ko];
#pragma unroll
      for (int nt = 0; nt < NTILES; ++nt) {
        short8 bh = *(const short8*)&s_bh[(nt*16 + m16)*SAS + ko];
        short8 bl = *(const short8*)&s_bl[(nt*16 + m16)*SAS + ko];
        acc[nt] = MFMA16(ah, bh, acc[nt]);
        acc[nt] = MFMA16(al, bh, acc[nt]);
        acc[nt] = MFMA16(ah, bl, acc[nt]);
      }
    }
  }
  __syncthreads();   // staging LDS dead; s_out may alias it

  // epilogue: C row = wv*16 + quad*4 + reg (pixel), col = nt*16 + m16 (oc)
#pragma unroll
  for (int nt = 0; nt < NTILES; ++nt) {
    int oc = nt*16 + m16;
    float bi = 0.f, sc = 1.f, sh = 0.f;
    if (oc < OC) {
      if constexpr (HASBIAS) bi = bias[oc];
      if constexpr (HASBN) {
        sc = bng[oc] * rsqrtf(bnv[oc] + 1e-5f);
        sh = bnb[oc] - bnm[oc] * sc;
      }
    }
#pragma unroll
    for (int reg = 0; reg < 4; ++reg) {
      int rowl = wv*16 + quad*4 + reg;
      float e = (acc[nt][reg] + bi) * sc + sh;
      if constexpr (RELU) e = fmaxf(e, 0.f);
      if constexpr (POOLMAX) {
        if (oc < OC) s_out[rowl*OCS + oc] = e;
      } else {
        if (oc < OC) out[((size_t)b*OC + oc)*HW + hw0 + rowl] = e;
      }
    }
  }
  if constexpr (POOLMAX) {
    __syncthreads();
    constexpr int PR = (64 / W) / 2, PC = W / 2, CNT = PR * PC * OC;
    const int r0 = hw0 / W;
    for (int e2 = tid; e2 < CNT; e2 += 256) {
      int oc = e2 % OC, q = e2 / OC, pc = q % PC, pr = q / PC;
      int base = ((2*pr)*W + 2*pc)*OCS + oc;
      float a0 = s_out[base],         a1 = s_out[base + OCS];
      float a2 = s_out[base + W*OCS], a3 = s_out[base + W*OCS + OCS];
      float m = fmaxf(fmaxf(a0, a1), fmaxf(a2, a3));
      out[(((size_t)b*OC + oc)*(H/2) + (r0 >> 1) + pr)*(W/2) + pc] = m;
    }
  }
}

// ---------------------------------------------------------------------------
// Small VALU conv (round-4, proven): used for conv5/conv6 (4x4 spatial).
// ---------------------------------------------------------------------------
template<int IC, int OC, int OCW, int H, int W, bool HASBN, bool RELU, int POOL>
__global__ __launch_bounds__(256) void k_conv(
    const float* __restrict__ in, const float* __restrict__ w,
    const float* __restrict__ bias,
    const float* __restrict__ bng, const float* __restrict__ bnb,
    const float* __restrict__ bnm, const float* __restrict__ bnv,
    float* __restrict__ out) {
  constexpr int HW    = H * W;
  constexpr int TPIX  = (HW < 64) ? HW : 64;
  constexpr int TILES = HW / TPIX;
  constexpr int NGRP  = 256 / TPIX;
  constexpr int OCA   = OCW / NGRP;
  constexpr int RT    = TPIX / W;
  constexpr int WP    = W + 2;
  constexpr int CH    = 4;
  constexpr int RROWS = RT + 2;
  constexpr int SIN   = CH * RROWS * WP;
  __shared__ float s_in[SIN];
  __shared__ __align__(16) float s_w[CH * 9 * OCW];
  const int tid = threadIdx.x;
  const int b   = blockIdx.x / TILES;
  const int r0  = (blockIdx.x % TILES) * RT;
  const int pix = tid % TPIX;
  const int ocg = tid / TPIX;
  const int r = pix / W, c = pix % W;
  float acc[OCA];
#pragma unroll
  for (int o = 0; o < OCA; ++o) acc[o] = 0.f;
  for (int cc = 0; cc < IC; cc += CH) {
    __syncthreads();
    for (int i = tid; i < SIN; i += 256) {
      int ci  = i / (RROWS * WP);
      int rem = i % (RROWS * WP);
      int rr  = rem / WP + r0 - 1;
      int cw  = rem % WP - 1;
      bool ok = (rr >= 0) && (rr < H) && (cw >= 0) && (cw < W);
      s_in[i] = ok ? in[(((size_t)b*IC + cc + ci)*H + rr)*W + cw] : 0.f;
    }
    for (int i = tid; i < CH * 9 * OCW; i += 256) {
      int oc = i % OCW, k = i / OCW;
      s_w[i] = (oc < OC) ? w[((size_t)oc*IC + cc + (k/9))*9 + (k%9)] : 0.f;
    }
    __syncthreads();
#pragma unroll
    for (int ci = 0; ci < CH; ++ci) {
      const float* sp = s_in + ci*RROWS*WP + r*WP + c;
#pragma unroll
      for (int n = 0; n < 9; ++n) {
        float v = sp[(n/3)*WP + (n%3)];
        const float4* w4 = (const float4*)(s_w + (ci*9 + n)*OCW + ocg*OCA);
#pragma unroll
        for (int o = 0; o < OCA/4; ++o) {
          float4 ww = w4[o];
          acc[4*o  ] = fmaf(v, ww.x, acc[4*o  ]);
          acc[4*o+1] = fmaf(v, ww.y, acc[4*o+1]);
          acc[4*o+2] = fmaf(v, ww.z, acc[4*o+2]);
          acc[4*o+3] = fmaf(v, ww.w, acc[4*o+3]);
        }
      }
    }
  }
#pragma unroll
  for (int o = 0; o < OCA; ++o) {
    int oc = ocg*OCA + o;
    float e = 0.f;
    if (oc < OC) {
      e = acc[o] + bias[oc];
      if constexpr (HASBN) {
        float sc = bng[oc] * rsqrtf(bnv[oc] + 1e-5f);
        e = e * sc + (bnb[oc] - bnm[oc]*sc);
      }
      if constexpr (RELU) e = fmaxf(e, 0.f);
    }
    if constexpr (POOL == 0) {
      if (oc < OC)
        out[(((size_t)b*OC + oc)*H + (r0 + r))*W + c] = e;
    } else {
      float e1 = __shfl_xor(e, 1);
      float e2 = __shfl_xor(e, W);
      float e3 = __shfl_xor(e, W + 1);
      float m = (POOL == 1) ? fmaxf(fmaxf(e, e1), fmaxf(e2, e3))
                            : (e + e1 + e2 + e3) * 0.25f;
      if (oc < OC && !(r & 1) && !(c & 1))
        out[(((size_t)b*OC + oc)*(H/2) + (r0 + r)/2)*(W/2) + (c/2)] = m;
    }
  }
}

__global__ __launch_bounds__(128) void k_fc(const float* __restrict__ in,
                                            const float* __restrict__ w,
                                            const float* __restrict__ bias,
                                            float* __restrict__ out) {
  int j = blockIdx.x, b = threadIdx.x;
  const float4* ib = (const float4*)(in + (size_t)b*512);
  const float4* wb = (const float4*)(w + (size_t)j*512);
  float acc = bias[j];
  for (int k = 0; k < 128; ++k) {
    float4 a = ib[k], q = wb[k];
    acc = fmaf(a.x, q.x, fmaf(a.y, q.y, fmaf(a.z, q.z, fmaf(a.w, q.w, acc))));
  }
  out[(size_t)b*200 + j] = acc;
}

__global__ __launch_bounds__(128) void k_fc1(const float* __restrict__ in,
                                             const float* __restrict__ w,
                                             const float* __restrict__ bias,
                                             float* __restrict__ out) {
  int j = blockIdx.x, b = threadIdx.x;
  const float4* ib = (const float4*)(in + (size_t)b*200);
  const float4* wb = (const float4*)(w + (size_t)j*200);
  float acc = bias[j];
  for (int k = 0; k < 50; ++k) {
    float4 a = ib[k], q = wb[k];
    acc = fmaf(a.x, q.x, fmaf(a.y, q.y, fmaf(a.z, q.z, fmaf(a.w, q.w, acc))));
  }
  out[(size_t)b*16 + j] = acc;
}

// ---------------------------------------------------------------------------
extern "C" void kernel_launch(void* const* d_in, const int* in_sizes, int n_in,
                              void* d_out, int out_size, void* d_ws, size_t ws_size,
                              hipStream_t stream) {
  const float* X    = (const float*)d_in[0];
  const float* D1PW = (const float*)d_in[1];
  const float* D1PB = (const float*)d_in[2];
  const float* D1W  = (const float*)d_in[3];
  const float* BN1G = (const float*)d_in[4];
  const float* BN1B = (const float*)d_in[5];
  const float* BN1M = (const float*)d_in[6];
  const float* BN1V = (const float*)d_in[7];
  const float* C2W  = (const float*)d_in[8];
  const float* C2B  = (const float*)d_in[9];
  const float* BN2G = (const float*)d_in[10];
  const float* BN2B = (const float*)d_in[11];
  const float* BN2M = (const float*)d_in[12];
  const float* BN2V = (const float*)d_in[13];
  const float* D3PW = (const float*)d_in[14];
  const float* D3PB = (const float*)d_in[15];
  const float* D3W  = (const float*)d_in[16];
  const float* BN3G = (const float*)d_in[17];
  const float* BN3B = (const float*)d_in[18];
  const float* BN3M = (const float*)d_in[19];
  const float* BN3V = (const float*)d_in[20];
  const float* C4W  = (const float*)d_in[21];
  const float* C4B  = (const float*)d_in[22];
  const float* BN4G = (const float*)d_in[23];
  const float* BN4B = (const float*)d_in[24];
  const float* BN4M = (const float*)d_in[25];
  const float* BN4V = (const float*)d_in[26];
  const float* C5W  = (const float*)d_in[27];
  const float* C5B  = (const float*)d_in[28];
  const float* BN5G = (const float*)d_in[29];
  const float* BN5B = (const float*)d_in[30];
  const float* BN5M = (const float*)d_in[31];
  const float* BN5V = (const float*)d_in[32];
  const float* C6W  = (const float*)d_in[33];
  const float* C6B  = (const float*)d_in[34];
  const float* BN6G = (const float*)d_in[35];
  const float* BN6B = (const float*)d_in[36];
  const float* BN6M = (const float*)d_in[37];
  const float* BN6V = (const float*)d_in[38];
  const float* FCW  = (const float*)d_in[39];
  const float* FCB  = (const float*)d_in[40];
  const float* FC1W = (const float*)d_in[41];
  const float* FC1B = (const float*)d_in[42];

  char* ws = (char*)d_ws;
  float* off1 = (float*)(ws + OFF1_B);
  float* h1   = (float*)(ws + H1_B);
  float* h2p  = (float*)(ws + H2P_B);
  float* off3 = (float*)(ws + OFF3_B);
  float* h3   = (float*)(ws + H3_B);
  float* h4p  = (float*)(ws + H4P_B);
  float* h5   = (float*)(ws + H5_B);
  float* h6p  = (float*)(ws + H6P_B);
  float* fco  = (float*)(ws + FCO_B);
  float* outp = (float*)d_out;

  // block 1: offset conv (MFMA) -> fused deform einsum (MFMA) + BN + ReLU
  k_gemm<false,200,18,32,2,16,16,true,false,false,false><<<512, 256, 0, stream>>>(
      X, nullptr, D1PW, D1PB, nullptr, nullptr, nullptr, nullptr, off1);
  k_gemm<true,200,96,96,6,16,16,false,true,true,false><<<512, 256, 0, stream>>>(
      X, off1, D1W, nullptr, BN1G, BN1B, BN1M, BN1V, h1);
  // block 2: conv + bias + BN + ReLU + maxpool (MFMA, fused)
  k_gemm<false,96,96,96,6,16,16,true,true,true,true><<<512, 256, 0, stream>>>(
      h1, nullptr, C2W, C2B, BN2G, BN2B, BN2M, BN2V, h2p);
  // block 3: offset conv -> deform einsum
  k_gemm<false,96,18,32,2,8,8,true,false,false,false><<<128, 256, 0, stream>>>(
      h2p, nullptr, D3PW, D3PB, nullptr, nullptr, nullptr, nullptr, off3);
  k_gemm<true,96,108,112,7,8,8,false,true,true,false><<<128, 256, 0, stream>>>(
      h2p, off3, D3W, nullptr, BN3G, BN3B, BN3M, BN3V, h3);
  // block 4: conv + bias + BN + ReLU + maxpool (MFMA, fused)
  k_gemm<false,108,108,112,7,8,8,true,true,true,true><<<128, 256, 0, stream>>>(
      h3, nullptr, C4W, C4B, BN4G, BN4B, BN4M, BN4V, h4p);
  // block 5: conv + BN + ReLU (VALU)
  k_conv<108,128,128,4,4,true,true,0><<<128, 256, 0, stream>>>(
      h4p, C5W, C5B, BN5G, BN5B, BN5M, BN5V, h5);
  // block 6: conv + BN + ReLU + avgpool (VALU, ReLU before avg)
  k_conv<128,128,128,4,4,true,true,2><<<128, 256, 0, stream>>>(
      h5, C6W, C6B, BN6G, BN6B, BN6M, BN6V, h6p);
  // classifier
  k_fc<<<200, 128, 0, stream>>>(h6p, FCW, FCB, fco);
  k_fc1<<<16, 128, 0, stream>>>(fco, FC1W, FC1B, outp);
}

// Round 6
// 853.850 us; speedup vs baseline: 3.5162x; 1.7655x over previous
//
#include <hip/hip_runtime.h>

typedef __attribute__((ext_vector_type(8))) short short8;
typedef __attribute__((ext_vector_type(4))) float f32x4;

#define MFMA16(a, b, c) __builtin_amdgcn_mfma_f32_16x16x32_bf16(a, b, c, 0, 0, 0)

__device__ __forceinline__ unsigned short f2bf(float x) {
  union { float f; unsigned u; } c; c.f = x;
  unsigned r = c.u + 0x7FFFu + ((c.u >> 16) & 1u);
  return (unsigned short)(r >> 16);
}
__device__ __forceinline__ float bf2f(unsigned short h) {
  union { unsigned u; float f; } c; c.u = ((unsigned)h) << 16; return c.f;
}

// ---------------------------------------------------------------------------
// Workspace (bytes). Peak 18.00 MB <= proven-safe 18,087,936.
// Packed weights [2][OCpad][Kpad] u16 (hi plane, lo plane), alive t0..conv4.
// off1 aliases the future h2p region (off1 dead before conv2 writes h2p).
// Phase-3 buffers reuse h1's slot (h1 dead after conv2).
// ---------------------------------------------------------------------------
static constexpr size_t PK_D1PW = 0;          // 32 x 1856
static constexpr size_t PK_D1W  = 237568;     // 96 x 1856
static constexpr size_t PK_C2W  = 950272;     // 96 x 896
static constexpr size_t PK_D3PW = 1294336;    // 32 x 896
static constexpr size_t PK_D3W  = 1409024;    // 112 x 896
static constexpr size_t PK_C4W  = 1810432;    // 112 x 1024  (ends 2,269,184)
static constexpr size_t OFF1_B  = 2269184;    // bf16 [128,18,256]  1,179,648
static constexpr size_t H2P_B   = 2269184;    // f32 [128,96,64]    3,145,728
static constexpr size_t H1_B    = 5414912;    // f32 [128,96,256]  12,582,912 (ends 17,997,824)
static constexpr size_t OFF3_B  = 5414912;    // bf16 [128,18,64]     294,912
static constexpr size_t H3_B    = 5709824;    // f32 [128,108,64]   3,538,944
static constexpr size_t H4P_B   = 9248768;    // f32 [128,108,16]     884,736
static constexpr size_t H5_B    = 10133504;   // f32 [128,128,16]   1,048,576
static constexpr size_t H6P_B   = 11182080;   // f32 [128,512]        262,144
static constexpr size_t FCO_B   = 11444224;   // f32 [128,200]        102,400

// ---------------------------------------------------------------------------
// Weight pre-pack: fp32 [OC][K] -> bf16 hi plane + lo plane [OCpad][Kpad],
// zero-padded (so OOB MFMA fragments multiply A by true zeros).
// ---------------------------------------------------------------------------
__global__ __launch_bounds__(256) void k_pack(const float* __restrict__ w,
                                              unsigned short* __restrict__ dst,
                                              int OC, int K, int OCpad, int Kpad) {
  int e = blockIdx.x * 256 + threadIdx.x;
  if (e >= OCpad * Kpad) return;
  int oc = e / Kpad, k = e - oc * Kpad;
  float v = (oc < OC && k < K) ? w[(size_t)oc * K + k] : 0.f;
  unsigned short hb = f2bf(v);
  dst[e] = hb;
  dst[(size_t)OCpad * Kpad + e] = f2bf(v - bf2f(hb));
}

// ---------------------------------------------------------------------------
// MFMA implicit-GEMM conv / deform-conv, split-bf16 x3, software-pipelined:
// panel p+1's gather/im2col + weight loads are issued into registers before
// mfma(p) and committed to LDS after the post-MFMA barrier.
// OUTMODE: 0 = f32 [b][oc][hw], 1 = bf16 (offset convs), 2 = f32 + maxpool2x2.
// ---------------------------------------------------------------------------
template<bool GATHER, int IC, int OC, int OCPAD, int NT, int H, int W,
         bool HASBIAS, bool HASBN, bool RELU, int OUTMODE, int MINW>
__global__ __launch_bounds__(256, MINW) void k_gemm(
    const float* __restrict__ in,              // [128,IC,H,W] f32
    const unsigned short* __restrict__ offb,   // [128,18,H,W] bf16 (GATHER)
    const unsigned short* __restrict__ wpk,    // packed [2][OCPAD][KPAD]
    const float* __restrict__ bias,
    const float* __restrict__ bng, const float* __restrict__ bnb,
    const float* __restrict__ bnm, const float* __restrict__ bnv,
    void* __restrict__ outv) {
  constexpr int HW   = H * W;
  constexpr int K    = IC * 9;
  constexpr int NP   = (K + 63) / 64;
  constexpr int KPAD = NP * 64;
  constexpr int TILES = HW / 64;
  constexpr int HP = H + 2, WPD = W + 2;
  constexpr int SAS = 72;                  // u16 per LDS row (64 + pad 8)
  constexpr int ASZ = 64 * SAS * 2;        // 9216 B
  constexpr int BSZ = OCPAD * SAS * 2;
  constexpr int TIDX = GATHER ? 576 * 4  : 0;  // uchar4 idx
  constexpr int TWT  = GATHER ? 576 * 16 : 0;  // float4 weights
  constexpr int PBST = TIDX + TWT + 2 * ASZ + 2 * BSZ;
  constexpr int SOUT = (OUTMODE == 2) ? 64 * (OC + 1) * 4 : 0;
  constexpr int PBYTES = (PBST > SOUT) ? PBST : SOUT;
  constexpr int NBV = (OCPAD * 8 + 255) / 256;   // short8 per plane per thread
  __shared__ __align__(16) char pool[PBYTES];
  uchar4* s_idx = (uchar4*)pool;
  float4* s_wt  = (float4*)(pool + TIDX);
  unsigned short* s_ah = (unsigned short*)(pool + TIDX + TWT);
  unsigned short* s_al = (unsigned short*)(pool + TIDX + TWT + ASZ);
  unsigned short* s_bh = (unsigned short*)(pool + TIDX + TWT + 2 * ASZ);
  unsigned short* s_bl = (unsigned short*)(pool + TIDX + TWT + 2 * ASZ + BSZ);
  float* s_out = (float*)pool;             // OUTMODE==2 only (after final sync)

  const int tid = threadIdx.x;
  const int b   = blockIdx.x / TILES;
  const int hw0 = (blockIdx.x % TILES) * 64;

  if constexpr (GATHER) {
    // bilinear gather table, exact reference formulas; zero-padding folded
    for (int i = tid; i < 576; i += 256) {
      int px = i / 9, n = i % 9;
      int h = (hw0 + px) / W, w = (hw0 + px) % W;
      float offx = bf2f(offb[(((size_t)b*18 + n)*HW) + h*W + w]);
      float offy = bf2f(offb[(((size_t)b*18 + 9 + n)*HW) + h*W + w]);
      float pxv = (float)(h + n/3) + offx;
      float pyv = (float)(w + n%3) + offy;
      pxv = fminf(fmaxf(pxv, 0.f), (float)(HP - 1));
      pyv = fminf(fmaxf(pyv, 0.f), (float)(WPD - 1));
      float x0 = floorf(pxv), y0 = floorf(pyv);
      float x1 = fminf(x0 + 1.f, (float)(HP - 1));
      float y1 = fminf(y0 + 1.f, (float)(WPD - 1));
      float glt = (1.f + x0 - pxv) * (1.f + y0 - pyv);
      float grb = (1.f - x1 + pxv) * (1.f - y1 + pyv);
      float glb = (1.f + x0 - pxv) * (1.f - y1 + pyv);
      float grt = (1.f - x1 + pxv) * (1.f + y0 - pyv);
      int   cx[4] = {(int)x0, (int)x1, (int)x0, (int)x1};
      int   cy[4] = {(int)y0, (int)y1, (int)y1, (int)y0};
      float gw[4] = {glt, grb, glb, grt};
      unsigned char id[4]; float gg[4];
#pragma unroll
      for (int q = 0; q < 4; ++q) {
        bool ok = (cx[q] >= 1) && (cx[q] <= H) && (cy[q] >= 1) && (cy[q] <= W);
        id[q] = ok ? (unsigned char)((cx[q]-1)*W + (cy[q]-1)) : (unsigned char)0;
        gg[q] = ok ? gw[q] : 0.f;
      }
      s_idx[i] = make_uchar4(id[0], id[1], id[2], id[3]);
      s_wt[i]  = make_float4(gg[0], gg[1], gg[2], gg[3]);
    }
  }
  __syncthreads();

  const int lane = tid & 63;
  const int wv   = tid >> 6;
  const int m16  = lane & 15;
  const int quad = lane >> 4;
  f32x4 acc[NT];
#pragma unroll
  for (int nt = 0; nt < NT; ++nt) acc[nt] = (f32x4){0.f, 0.f, 0.f, 0.f};

  float  rva[16][4];   // GATHER raw corners (in-flight across mfma)
  float  rvs[16];      // im2col raw values
  short8 rb[2][NBV];   // B panel slices

  auto prefA = [&](int k0) {
#pragma unroll
    for (int j = 0; j < 16; ++j) {
      int e = tid + 256*j;
      int px = e >> 6, kk = e & 63, k = k0 + kk;
      if (k < K) {
        int ci = k / 9, n = k - ci * 9;
        if constexpr (GATHER) {
          uchar4 t4 = s_idx[px*9 + n];
          const float* pb = in + ((size_t)b*IC + ci)*HW;
          rva[j][0] = pb[t4.x]; rva[j][1] = pb[t4.y];
          rva[j][2] = pb[t4.z]; rva[j][3] = pb[t4.w];
        } else {
          int hw = hw0 + px, r = hw / W, c = hw % W;
          int rr = r + n/3 - 1, cc = c + n%3 - 1;
          rvs[j] = (rr >= 0 && rr < H && cc >= 0 && cc < W)
                 ? in[((size_t)b*IC + ci)*HW + rr*W + cc] : 0.f;
        }
      }
    }
#pragma unroll
    for (int pl = 0; pl < 2; ++pl)
#pragma unroll
      for (int j = 0; j < NBV; ++j) {
        int e = tid + 256*j;
        if (e < OCPAD*8) {
          int oc = e >> 3, kb = e & 7;
          rb[pl][j] = *(const short8*)(wpk + (size_t)pl*OCPAD*KPAD
                                       + (size_t)oc*KPAD + k0 + kb*8);
        }
      }
  };

  auto commit = [&](int k0) {
#pragma unroll
    for (int j = 0; j < 16; ++j) {
      int e = tid + 256*j;
      int px = e >> 6, kk = e & 63, k = k0 + kk;
      float v = 0.f;
      if (k < K) {
        if constexpr (GATHER) {
          int ci = k / 9, n = k - ci * 9;
          float4 w4 = s_wt[px*9 + n];
          v = w4.x*rva[j][0] + w4.y*rva[j][1] + w4.z*rva[j][2] + w4.w*rva[j][3];
        } else {
          v = rvs[j];
        }
      }
      unsigned short hb = f2bf(v);
      s_ah[px*SAS + kk] = hb;
      s_al[px*SAS + kk] = f2bf(v - bf2f(hb));
    }
#pragma unroll
    for (int pl = 0; pl < 2; ++pl)
#pragma unroll
      for (int j = 0; j < NBV; ++j) {
        int e = tid + 256*j;
        if (e < OCPAD*8) {
          int oc = e >> 3, kb = e & 7;
          *(short8*)((pl ? s_bl : s_bh) + oc*SAS + kb*8) = rb[pl][j];
        }
      }
  };

  prefA(0);
  for (int p = 0; p < NP; ++p) {
    commit(p * 64);
    if (p + 1 < NP) prefA((p + 1) * 64);   // loads fly during mfma(p)
    __syncthreads();
#pragma unroll
    for (int ks = 0; ks < 2; ++ks) {
      const int ko = ks*32 + quad*8;
      short8 ah = *(const short8*)&s_ah[(wv*16 + m16)*SAS + ko];
      short8 al = *(const short8*)&s_al[(wv*16 + m16)*SAS + ko];
#pragma unroll
      for (int nt = 0; nt < NT; ++nt) {
        short8 bh = *(const short8*)&s_bh[(nt*16 + m16)*SAS + ko];
        short8 bl = *(const short8*)&s_bl[(nt*16 + m16)*SAS + ko];
        acc[nt] = MFMA16(ah, bh, acc[nt]);
        acc[nt] = MFMA16(al, bh, acc[nt]);
        acc[nt] = MFMA16(ah, bl, acc[nt]);
      }
    }
    __syncthreads();
  }

  // epilogue: C row = wv*16 + quad*4 + reg (pixel), col = nt*16 + m16 (oc)
  constexpr int OCS = OC + 1;
#pragma unroll
  for (int nt = 0; nt < NT; ++nt) {
    int oc = nt*16 + m16;
    float bi = 0.f, sc = 1.f, sh = 0.f;
    if (oc < OC) {
      if constexpr (HASBIAS) bi = bias[oc];
      if constexpr (HASBN) {
        sc = bng[oc] * rsqrtf(bnv[oc] + 1e-5f);
        sh = bnb[oc] - bnm[oc] * sc;
      }
    }
#pragma unroll
    for (int reg = 0; reg < 4; ++reg) {
      int rowl = wv*16 + quad*4 + reg;
      float e = (acc[nt][reg] + bi) * sc + sh;
      if constexpr (RELU) e = fmaxf(e, 0.f);
      if (oc < OC) {
        if constexpr (OUTMODE == 0) {
          ((float*)outv)[((size_t)b*OC + oc)*HW + hw0 + rowl] = e;
        } else if constexpr (OUTMODE == 1) {
          ((unsigned short*)outv)[((size_t)b*OC + oc)*HW + hw0 + rowl] = f2bf(e);
        } else {
          s_out[rowl*OCS + oc] = e;
        }
      }
    }
  }
  if constexpr (OUTMODE == 2) {
    __syncthreads();
    constexpr int PR = (64 / W) / 2, PC = W / 2, CNT = PR * PC * OC;
    const int r0 = hw0 / W;
    float* out = (float*)outv;
    for (int e2 = tid; e2 < CNT; e2 += 256) {
      int oc = e2 % OC, q = e2 / OC, pc = q % PC, pr = q / PC;
      int base = ((2*pr)*W + 2*pc)*OCS + oc;
      float a0 = s_out[base],         a1 = s_out[base + OCS];
      float a2 = s_out[base + W*OCS], a3 = s_out[base + W*OCS + OCS];
      float m = fmaxf(fmaxf(a0, a1), fmaxf(a2, a3));
      out[(((size_t)b*OC + oc)*(H/2) + (r0 >> 1) + pr)*(W/2) + pc] = m;
    }
  }
}

// ---------------------------------------------------------------------------
// Small VALU conv (proven): conv5 / conv6 (4x4 spatial).
// ---------------------------------------------------------------------------
template<int IC, int OC, int OCW, int H, int W, bool HASBN, bool RELU, int POOL>
__global__ __launch_bounds__(256) void k_conv(
    const float* __restrict__ in, const float* __restrict__ w,
    const float* __restrict__ bias,
    const float* __restrict__ bng, const float* __restrict__ bnb,
    const float* __restrict__ bnm, const float* __restrict__ bnv,
    float* __restrict__ out) {
  constexpr int HW    = H * W;
  constexpr int TPIX  = (HW < 64) ? HW : 64;
  constexpr int TILES = HW / TPIX;
  constexpr int NGRP  = 256 / TPIX;
  constexpr int OCA   = OCW / NGRP;
  constexpr int RT    = TPIX / W;
  constexpr int WP    = W + 2;
  constexpr int CH    = 4;
  constexpr int RROWS = RT + 2;
  constexpr int SIN   = CH * RROWS * WP;
  __shared__ float s_in[SIN];
  __shared__ __align__(16) float s_w[CH * 9 * OCW];
  const int tid = threadIdx.x;
  const int b   = blockIdx.x / TILES;
  const int r0  = (blockIdx.x % TILES) * RT;
  const int pix = tid % TPIX;
  const int ocg = tid / TPIX;
  const int r = pix / W, c = pix % W;
  float acc[OCA];
#pragma unroll
  for (int o = 0; o < OCA; ++o) acc[o] = 0.f;
  for (int cc = 0; cc < IC; cc += CH) {
    __syncthreads();
    for (int i = tid; i < SIN; i += 256) {
      int ci  = i / (RROWS * WP);
      int rem = i % (RROWS * WP);
      int rr  = rem / WP + r0 - 1;
      int cw  = rem % WP - 1;
      bool ok = (rr >= 0) && (rr < H) && (cw >= 0) && (cw < W);
      s_in[i] = ok ? in[(((size_t)b*IC + cc + ci)*H + rr)*W + cw] : 0.f;
    }
    for (int i = tid; i < CH * 9 * OCW; i += 256) {
      int oc = i % OCW, k = i / OCW;
      s_w[i] = (oc < OC) ? w[((size_t)oc*IC + cc + (k/9))*9 + (k%9)] : 0.f;
    }
    __syncthreads();
#pragma unroll
    for (int ci = 0; ci < CH; ++ci) {
      const float* sp = s_in + ci*RROWS*WP + r*WP + c;
#pragma unroll
      for (int n = 0; n < 9; ++n) {
        float v = sp[(n/3)*WP + (n%3)];
        const float4* w4 = (const float4*)(s_w + (ci*9 + n)*OCW + ocg*OCA);
#pragma unroll
        for (int o = 0; o < OCA/4; ++o) {
          float4 ww = w4[o];
          acc[4*o  ] = fmaf(v, ww.x, acc[4*o  ]);
          acc[4*o+1] = fmaf(v, ww.y, acc[4*o+1]);
          acc[4*o+2] = fmaf(v, ww.z, acc[4*o+2]);
          acc[4*o+3] = fmaf(v, ww.w, acc[4*o+3]);
        }
      }
    }
  }
#pragma unroll
  for (int o = 0; o < OCA; ++o) {
    int oc = ocg*OCA + o;
    float e = 0.f;
    if (oc < OC) {
      e = acc[o] + bias[oc];
      if constexpr (HASBN) {
        float sc = bng[oc] * rsqrtf(bnv[oc] + 1e-5f);
        e = e * sc + (bnb[oc] - bnm[oc]*sc);
      }
      if constexpr (RELU) e = fmaxf(e, 0.f);
    }
    if constexpr (POOL == 0) {
      if (oc < OC)
        out[(((size_t)b*OC + oc)*H + (r0 + r))*W + c] = e;
    } else {
      float e1 = __shfl_xor(e, 1);
      float e2 = __shfl_xor(e, W);
      float e3 = __shfl_xor(e, W + 1);
      float m = (POOL == 1) ? fmaxf(fmaxf(e, e1), fmaxf(e2, e3))
                            : (e + e1 + e2 + e3) * 0.25f;
      if (oc < OC && !(r & 1) && !(c & 1))
        out[(((size_t)b*OC + oc)*(H/2) + (r0 + r)/2)*(W/2) + (c/2)] = m;
    }
  }
}

__global__ __launch_bounds__(128) void k_fc(const float* __restrict__ in,
                                            const float* __restrict__ w,
                                            const float* __restrict__ bias,
                                            float* __restrict__ out) {
  int j = blockIdx.x, b = threadIdx.x;
  const float4* ib = (const float4*)(in + (size_t)b*512);
  const float4* wb = (const float4*)(w + (size_t)j*512);
  float acc = bias[j];
  for (int k = 0; k < 128; ++k) {
    float4 a = ib[k], q = wb[k];
    acc = fmaf(a.x, q.x, fmaf(a.y, q.y, fmaf(a.z, q.z, fmaf(a.w, q.w, acc))));
  }
  out[(size_t)b*200 + j] = acc;
}

__global__ __launch_bounds__(128) void k_fc1(const float* __restrict__ in,
                                             const float* __restrict__ w,
                                             const float* __restrict__ bias,
                                             float* __restrict__ out) {
  int j = blockIdx.x, b = threadIdx.x;
  const float4* ib = (const float4*)(in + (size_t)b*200);
  const float4* wb = (const float4*)(w + (size_t)j*200);
  float acc = bias[j];
  for (int k = 0; k < 50; ++k) {
    float4 a = ib[k], q = wb[k];
    acc = fmaf(a.x, q.x, fmaf(a.y, q.y, fmaf(a.z, q.z, fmaf(a.w, q.w, acc))));
  }
  out[(size_t)b*16 + j] = acc;
}

// ---------------------------------------------------------------------------
extern "C" void kernel_launch(void* const* d_in, const int* in_sizes, int n_in,
                              void* d_out, int out_size, void* d_ws, size_t ws_size,
                              hipStream_t stream) {
  const float* X    = (const float*)d_in[0];
  const float* D1PW = (const float*)d_in[1];
  const float* D1PB = (const float*)d_in[2];
  const float* D1W  = (const float*)d_in[3];
  const float* BN1G = (const float*)d_in[4];
  const float* BN1B = (const float*)d_in[5];
  const float* BN1M = (const float*)d_in[6];
  const float* BN1V = (const float*)d_in[7];
  const float* C2W  = (const float*)d_in[8];
  const float* C2B  = (const float*)d_in[9];
  const float* BN2G = (const float*)d_in[10];
  const float* BN2B = (const float*)d_in[11];
  const float* BN2M = (const float*)d_in[12];
  const float* BN2V = (const float*)d_in[13];
  const float* D3PW = (const float*)d_in[14];
  const float* D3PB = (const float*)d_in[15];
  const float* D3W  = (const float*)d_in[16];
  const float* BN3G = (const float*)d_in[17];
  const float* BN3B = (const float*)d_in[18];
  const float* BN3M = (const float*)d_in[19];
  const float* BN3V = (const float*)d_in[20];
  const float* C4W  = (const float*)d_in[21];
  const float* C4B  = (const float*)d_in[22];
  const float* BN4G = (const float*)d_in[23];
  const float* BN4B = (const float*)d_in[24];
  const float* BN4M = (const float*)d_in[25];
  const float* BN4V = (const float*)d_in[26];
  const float* C5W  = (const float*)d_in[27];
  const float* C5B  = (const float*)d_in[28];
  const float* BN5G = (const float*)d_in[29];
  const float* BN5B = (const float*)d_in[30];
  const float* BN5M = (const float*)d_in[31];
  const float* BN5V = (const float*)d_in[32];
  const float* C6W  = (const float*)d_in[33];
  const float* C6B  = (const float*)d_in[34];
  const float* BN6G = (const float*)d_in[35];
  const float* BN6B = (const float*)d_in[36];
  const float* BN6M = (const float*)d_in[37];
  const float* BN6V = (const float*)d_in[38];
  const float* FCW  = (const float*)d_in[39];
  const float* FCB  = (const float*)d_in[40];
  const float* FC1W = (const float*)d_in[41];
  const float* FC1B = (const float*)d_in[42];

  char* ws = (char*)d_ws;
  unsigned short* pk_d1pw = (unsigned short*)(ws + PK_D1PW);
  unsigned short* pk_d1w  = (unsigned short*)(ws + PK_D1W);
  unsigned short* pk_c2w  = (unsigned short*)(ws + PK_C2W);
  unsigned short* pk_d3pw = (unsigned short*)(ws + PK_D3PW);
  unsigned short* pk_d3w  = (unsigned short*)(ws + PK_D3W);
  unsigned short* pk_c4w  = (unsigned short*)(ws + PK_C4W);
  unsigned short* off1 = (unsigned short*)(ws + OFF1_B);
  unsigned short* off3 = (unsigned short*)(ws + OFF3_B);
  float* h1   = (float*)(ws + H1_B);
  float* h2p  = (float*)(ws + H2P_B);
  float* h3   = (float*)(ws + H3_B);
  float* h4p  = (float*)(ws + H4P_B);
  float* h5   = (float*)(ws + H5_B);
  float* h6p  = (float*)(ws + H6P_B);
  float* fco  = (float*)(ws + FCO_B);
  float* outp = (float*)d_out;

  // weight pre-pack (bf16 hi/lo planes, zero-padded)
  k_pack<<<232, 256, 0, stream>>>(D1PW, pk_d1pw,  18, 1800,  32, 1856);
  k_pack<<<696, 256, 0, stream>>>(D1W,  pk_d1w,   96, 1800,  96, 1856);
  k_pack<<<336, 256, 0, stream>>>(C2W,  pk_c2w,   96,  864,  96,  896);
  k_pack<<<112, 256, 0, stream>>>(D3PW, pk_d3pw,  18,  864,  32,  896);
  k_pack<<<392, 256, 0, stream>>>(D3W,  pk_d3w,  108,  864, 112,  896);
  k_pack<<<448, 256, 0, stream>>>(C4W,  pk_c4w,  108,  972, 112, 1024);

  // block 1: offset conv -> deform einsum + BN + ReLU
  k_gemm<false,200,18,32,2,16,16,true,false,false,1,4><<<512, 256, 0, stream>>>(
      X, nullptr, pk_d1pw, D1PB, nullptr, nullptr, nullptr, nullptr, off1);
  k_gemm<true,200,96,96,6,16,16,false,true,true,0,2><<<512, 256, 0, stream>>>(
      X, off1, pk_d1w, nullptr, BN1G, BN1B, BN1M, BN1V, h1);
  // block 2: conv + bias + BN + ReLU + maxpool
  k_gemm<false,96,96,96,6,16,16,true,true,true,2,3><<<512, 256, 0, stream>>>(
      h1, nullptr, pk_c2w, C2B, BN2G, BN2B, BN2M, BN2V, h2p);
  // block 3: offset conv -> deform einsum + BN + ReLU
  k_gemm<false,96,18,32,2,8,8,true,false,false,1,4><<<128, 256, 0, stream>>>(
      h2p, nullptr, pk_d3pw, D3PB, nullptr, nullptr, nullptr, nullptr, off3);
  k_gemm<true,96,108,112,7,8,8,false,true,true,0,2><<<128, 256, 0, stream>>>(
      h2p, off3, pk_d3w, nullptr, BN3G, BN3B, BN3M, BN3V, h3);
  // block 4: conv + bias + BN + ReLU + maxpool
  k_gemm<false,108,108,112,7,8,8,true,true,true,2,3><<<128, 256, 0, stream>>>(
      h3, nullptr, pk_c4w, C4B, BN4G, BN4B, BN4M, BN4V, h4p);
  // block 5: conv + BN + ReLU (VALU)
  k_conv<108,128,128,4,4,true,true,0><<<128, 256, 0, stream>>>(
      h4p, C5W, C5B, BN5G, BN5B, BN5M, BN5V, h5);
  // block 6: conv + BN + ReLU + avgpool (VALU, ReLU before avg)
  k_conv<128,128,128,4,4,true,true,2><<<128, 256, 0, stream>>>(
      h5, C6W, C6B, BN6G, BN6B, BN6M, BN6V, h6p);
  // classifier
  k_fc<<<200, 128, 0, stream>>>(h6p, FCW, FCB, fco);
  k_fc1<<<16, 128, 0, stream>>>(fco, FC1W, FC1B, outp);
}

// Round 7
// 754.250 us; speedup vs baseline: 3.9805x; 1.1321x over previous
//
#include <hip/hip_runtime.h>

typedef __attribute__((ext_vector_type(8))) short short8;
typedef __attribute__((ext_vector_type(4))) float f32x4;

#define MFMA16(a, b, c) __builtin_amdgcn_mfma_f32_16x16x32_bf16(a, b, c, 0, 0, 0)

__device__ __forceinline__ unsigned short f2bf(float x) {
  union { float f; unsigned u; } c; c.f = x;
  unsigned r = c.u + 0x7FFFu + ((c.u >> 16) & 1u);
  return (unsigned short)(r >> 16);
}
__device__ __forceinline__ float bf2f(unsigned short h) {
  union { unsigned u; float f; } c; c.u = ((unsigned)h) << 16; return c.f;
}

// ---------------------------------------------------------------------------
// Workspace (bytes). Peak 18.00 MB <= proven-safe 18,087,936. Same as r6.
// ---------------------------------------------------------------------------
static constexpr size_t PK_D1PW = 0;          // 32 x 1856
static constexpr size_t PK_D1W  = 237568;     // 96 x 1856
static constexpr size_t PK_C2W  = 950272;     // 96 x 896
static constexpr size_t PK_D3PW = 1294336;    // 32 x 896
static constexpr size_t PK_D3W  = 1409024;    // 112 x 896
static constexpr size_t PK_C4W  = 1810432;    // 112 x 1024  (ends 2,269,184)
static constexpr size_t OFF1_B  = 2269184;    // bf16 [128,18,256]  1,179,648
static constexpr size_t H2P_B   = 2269184;    // f32 [128,96,64]    3,145,728
static constexpr size_t H1_B    = 5414912;    // f32 [128,96,256]  12,582,912 (ends 17,997,824)
static constexpr size_t OFF3_B  = 5414912;    // bf16 [128,18,64]     294,912
static constexpr size_t H3_B    = 5709824;    // f32 [128,108,64]   3,538,944
static constexpr size_t H4P_B   = 9248768;    // f32 [128,108,16]     884,736
static constexpr size_t H5_B    = 10133504;   // f32 [128,128,16]   1,048,576
static constexpr size_t H6P_B   = 11182080;   // f32 [128,512]        262,144
static constexpr size_t FCO_B   = 11444224;   // f32 [128,200]        102,400

__global__ __launch_bounds__(256) void k_pack(const float* __restrict__ w,
                                              unsigned short* __restrict__ dst,
                                              int OC, int K, int OCpad, int Kpad) {
  int e = blockIdx.x * 256 + threadIdx.x;
  if (e >= OCpad * Kpad) return;
  int oc = e / Kpad, k = e - oc * Kpad;
  float v = (oc < OC && k < K) ? w[(size_t)oc * K + k] : 0.f;
  unsigned short hb = f2bf(v);
  dst[e] = hb;
  dst[(size_t)OCpad * Kpad + e] = f2bf(v - bf2f(hb));
}

// ---------------------------------------------------------------------------
// MFMA implicit-GEMM conv / deform-conv, split-bf16 x3.
// KEY CHANGE (r7): the per-panel input planes (<=8 channels, <=8KB) are
// pipelined global->regs->LDS (coalesced, double-buffered s_x, depth-2 reg
// prefetch). Gather / im2col reads come from LDS (ds_read_b32), eliminating
// the scattered-global address-rate bottleneck identified in r6. A-commit
// writes b128 (thread owns one pixel x 16 contiguous k).
// OUTMODE: 0 = f32 [b][oc][hw], 1 = bf16 (offset convs), 2 = f32 + maxpool2x2.
// ---------------------------------------------------------------------------
template<bool GATHER, int IC, int OC, int OCPAD, int NT, int H, int W,
         bool HASBIAS, bool HASBN, bool RELU, int OUTMODE>
__global__ __launch_bounds__(256, 2) void k_gemm(
    const float* __restrict__ in,              // [128,IC,H,W] f32
    const unsigned short* __restrict__ offb,   // [128,18,H,W] bf16 (GATHER)
    const unsigned short* __restrict__ wpk,    // packed [2][OCPAD][KPAD]
    const float* __restrict__ bias,
    const float* __restrict__ bng, const float* __restrict__ bnb,
    const float* __restrict__ bnm, const float* __restrict__ bnv,
    void* __restrict__ outv) {
  constexpr int HW   = H * W;
  constexpr int K    = IC * 9;
  constexpr int NP   = (K + 63) / 64;
  constexpr int KPAD = NP * 64;
  constexpr int TILES = HW / 64;
  constexpr int HP = H + 2, WPD = W + 2;
  constexpr int SAS = 72;                   // u16 per A/B LDS row (64 + pad)
  constexpr int ASZ = 64 * SAS * 2;         // 9216 B
  constexpr int BSZ = OCPAD * SAS * 2;
  constexpr int SXS = HW + 8;               // f32 per input plane row (+pad)
  constexpr int SXSZ = 8 * SXS * 4;         // one s_x buffer (8 planes)
  constexpr int CPT = HW / 32;              // f32 per thread in plane staging
  constexpr int TIDX = GATHER ? 576 * 4  : 0;
  constexpr int TWT  = GATHER ? 576 * 16 : 0;
  constexpr int PBST = TIDX + TWT + 2*ASZ + 2*BSZ + 2*SXSZ;
  constexpr int SOUTB = (OUTMODE == 2) ? 64 * (OC + 1) * 4 : 0;
  constexpr int PBYTES = (PBST > SOUTB) ? PBST : SOUTB;
  constexpr int NBV = (OCPAD * 8 + 255) / 256;
  __shared__ __align__(16) char pool[PBYTES];
  uchar4* s_idx = (uchar4*)pool;
  float4* s_wt  = (float4*)(pool + TIDX);
  unsigned short* s_ah = (unsigned short*)(pool + TIDX + TWT);
  unsigned short* s_al = (unsigned short*)(pool + TIDX + TWT + ASZ);
  unsigned short* s_bh = (unsigned short*)(pool + TIDX + TWT + 2*ASZ);
  unsigned short* s_bl = (unsigned short*)(pool + TIDX + TWT + 2*ASZ + BSZ);
  float* s_x = (float*)(pool + TIDX + TWT + 2*ASZ + 2*BSZ);
  float* s_out = (float*)pool;              // OUTMODE==2 (aliases, after sync)

  const int tid = threadIdx.x;
  const int b   = blockIdx.x / TILES;
  const int hw0 = (blockIdx.x % TILES) * 64;
  const float* __restrict__ inb = in + (size_t)b * IC * HW;

  if constexpr (GATHER) {
    for (int i = tid; i < 576; i += 256) {
      int px = i / 9, n = i % 9;
      int h = (hw0 + px) / W, w = (hw0 + px) % W;
      float offx = bf2f(offb[(((size_t)b*18 + n)*HW) + h*W + w]);
      float offy = bf2f(offb[(((size_t)b*18 + 9 + n)*HW) + h*W + w]);
      float pxv = (float)(h + n/3) + offx;
      float pyv = (float)(w + n%3) + offy;
      pxv = fminf(fmaxf(pxv, 0.f), (float)(HP - 1));
      pyv = fminf(fmaxf(pyv, 0.f), (float)(WPD - 1));
      float x0 = floorf(pxv), y0 = floorf(pyv);
      float x1 = fminf(x0 + 1.f, (float)(HP - 1));
      float y1 = fminf(y0 + 1.f, (float)(WPD - 1));
      float glt = (1.f + x0 - pxv) * (1.f + y0 - pyv);
      float grb = (1.f - x1 + pxv) * (1.f - y1 + pyv);
      float glb = (1.f + x0 - pxv) * (1.f - y1 + pyv);
      float grt = (1.f - x1 + pxv) * (1.f + y0 - pyv);
      int   cx[4] = {(int)x0, (int)x1, (int)x0, (int)x1};
      int   cy[4] = {(int)y0, (int)y1, (int)y1, (int)y0};
      float gw[4] = {glt, grb, glb, grt};
      unsigned char id[4]; float gg[4];
#pragma unroll
      for (int q = 0; q < 4; ++q) {
        bool ok = (cx[q] >= 1) && (cx[q] <= H) && (cy[q] >= 1) && (cy[q] <= W);
        id[q] = ok ? (unsigned char)((cx[q]-1)*W + (cy[q]-1)) : (unsigned char)0;
        gg[q] = ok ? gw[q] : 0.f;
      }
      s_idx[i] = make_uchar4(id[0], id[1], id[2], id[3]);
      s_wt[i]  = make_float4(gg[0], gg[1], gg[2], gg[3]);
    }
  }

  const int lane = tid & 63;
  const int wv   = tid >> 6;
  const int m16  = lane & 15;
  const int quad = lane >> 4;
  const int px   = tid >> 2;             // A-commit: pixel owned by thread
  const int kb   = (tid & 3) * 16;       // A-commit: 16-k slice
  const int xpl  = tid >> 5;             // plane staging: plane index
  const int xo   = (tid & 31) * CPT;     // plane staging: in-plane offset
  f32x4 acc[NT];
#pragma unroll
  for (int nt = 0; nt < NT; ++nt) acc[nt] = (f32x4){0.f, 0.f, 0.f, 0.f};

  float  rx[2][CPT];
  short8 rb[2][NBV];

  auto ci0_of = [&](int p) { int c = (p*64)/9; return (c > IC-8) ? IC-8 : c; };

  auto prefX = [&](int p) {
    if (p >= NP) return;
    const float* s = inb + (size_t)(ci0_of(p) + xpl)*HW + xo;
    if constexpr (CPT == 8) {
      float4 a = ((const float4*)s)[0], c = ((const float4*)s)[1];
      rx[p&1][0]=a.x; rx[p&1][1]=a.y; rx[p&1][2]=a.z; rx[p&1][3]=a.w;
      rx[p&1][4]=c.x; rx[p&1][5]=c.y; rx[p&1][6]=c.z; rx[p&1][7]=c.w;
    } else {
      float2 a = ((const float2*)s)[0];
      rx[p&1][0]=a.x; rx[p&1][1]=a.y;
    }
  };
  auto commitX = [&](int p) {
    if (p >= NP) return;
    float* d = s_x + (size_t)(p&1)*8*SXS + xpl*SXS + xo;
    if constexpr (CPT == 8) {
      ((float4*)d)[0] = make_float4(rx[p&1][0],rx[p&1][1],rx[p&1][2],rx[p&1][3]);
      ((float4*)d)[1] = make_float4(rx[p&1][4],rx[p&1][5],rx[p&1][6],rx[p&1][7]);
    } else {
      ((float2*)d)[0] = make_float2(rx[p&1][0],rx[p&1][1]);
    }
  };
  auto prefB = [&](int p) {
    if (p >= NP) return;
    const int k0 = p * 64;
#pragma unroll
    for (int pl = 0; pl < 2; ++pl)
#pragma unroll
      for (int j = 0; j < NBV; ++j) {
        int e = tid + 256*j;
        if (e < OCPAD*8) {
          int oc = e >> 3, kq = e & 7;
          rb[pl][j] = *(const short8*)(wpk + (size_t)pl*OCPAD*KPAD
                                       + (size_t)oc*KPAD + k0 + kq*8);
        }
      }
  };
  auto commitB = [&]() {
#pragma unroll
    for (int pl = 0; pl < 2; ++pl)
#pragma unroll
      for (int j = 0; j < NBV; ++j) {
        int e = tid + 256*j;
        if (e < OCPAD*8) {
          int oc = e >> 3, kq = e & 7;
          *(short8*)((pl ? s_bl : s_bh) + oc*SAS + kq*8) = rb[pl][j];
        }
      }
  };

  prefX(0); prefB(0); commitX(0); prefX(1);
  __syncthreads();

  for (int p = 0; p < NP; ++p) {
    const int k0 = p * 64;
    const int ci0c = ci0_of(p);
    const float* xb = s_x + (size_t)(p&1)*8*SXS;
    // ---- A commit: gather / im2col from LDS planes, split to bf16 hi/lo ----
    float v[16];
    {
      const int kbase = k0 + kb;
      int ci = kbase / 9, n = kbase - ci*9;
      int r = 0, c = 0;
      if constexpr (!GATHER) { int hw = hw0 + px; r = hw / W; c = hw % W; }
#pragma unroll
      for (int i = 0; i < 16; ++i) {
        float val = 0.f;
        if (kbase + i < K) {
          if constexpr (GATHER) {
            uchar4 t4 = s_idx[px*9 + n];
            float4 w4 = s_wt[px*9 + n];
            const float* xp = xb + (ci - ci0c)*SXS;
            val = w4.x*xp[t4.x] + w4.y*xp[t4.y] + w4.z*xp[t4.z] + w4.w*xp[t4.w];
          } else {
            int rr = r + n/3 - 1, cc = c + n%3 - 1;
            if (rr >= 0 && rr < H && cc >= 0 && cc < W)
              val = xb[(ci - ci0c)*SXS + rr*W + cc];
          }
        }
        v[i] = val;
        if (++n == 9) { n = 0; ++ci; }
      }
    }
    {
      short8 vh0, vh1, vl0, vl1;
#pragma unroll
      for (int i = 0; i < 16; ++i) {
        unsigned short hb = f2bf(v[i]);
        unsigned short lb = f2bf(v[i] - bf2f(hb));
        if (i < 8) { vh0[i] = (short)hb; vl0[i] = (short)lb; }
        else       { vh1[i-8] = (short)hb; vl1[i-8] = (short)lb; }
      }
      *(short8*)&s_ah[px*SAS + kb]     = vh0;
      *(short8*)&s_ah[px*SAS + kb + 8] = vh1;
      *(short8*)&s_al[px*SAS + kb]     = vl0;
      *(short8*)&s_al[px*SAS + kb + 8] = vl1;
    }
    commitB();
    commitX(p + 1);
    prefB(p + 1);
    prefX(p + 2);
    __syncthreads();
#pragma unroll
    for (int ks = 0; ks < 2; ++ks) {
      const int ko = ks*32 + quad*8;
      short8 ah = *(const short8*)&s_ah[(wv*16 + m16)*SAS + ko];
      short8 al = *(const short8*)&s_al[(wv*16 + m16)*SAS + ko];
#pragma unroll
      for (int nt = 0; nt < NT; ++nt) {
        short8 bh = *(const short8*)&s_bh[(nt*16 + m16)*SAS + ko];
        short8 bl = *(const short8*)&s_bl[(nt*16 + m16)*SAS + ko];
        acc[nt] = MFMA16(ah, bh, acc[nt]);
        acc[nt] = MFMA16(al, bh, acc[nt]);
        acc[nt] = MFMA16(ah, bl, acc[nt]);
      }
    }
    __syncthreads();
  }

  // epilogue: C row = wv*16 + quad*4 + reg (pixel), col = nt*16 + m16 (oc)
  constexpr int OCS = OC + 1;
#pragma unroll
  for (int nt = 0; nt < NT; ++nt) {
    int oc = nt*16 + m16;
    float bi = 0.f, sc = 1.f, sh = 0.f;
    if (oc < OC) {
      if constexpr (HASBIAS) bi = bias[oc];
      if constexpr (HASBN) {
        sc = bng[oc] * rsqrtf(bnv[oc] + 1e-5f);
        sh = bnb[oc] - bnm[oc] * sc;
      }
    }
#pragma unroll
    for (int reg = 0; reg < 4; ++reg) {
      int rowl = wv*16 + quad*4 + reg;
      float e = (acc[nt][reg] + bi) * sc + sh;
      if constexpr (RELU) e = fmaxf(e, 0.f);
      if (oc < OC) {
        if constexpr (OUTMODE == 0) {
          ((float*)outv)[((size_t)b*OC + oc)*HW + hw0 + rowl] = e;
        } else if constexpr (OUTMODE == 1) {
          ((unsigned short*)outv)[((size_t)b*OC + oc)*HW + hw0 + rowl] = f2bf(e);
        } else {
          s_out[rowl*OCS + oc] = e;
        }
      }
    }
  }
  if constexpr (OUTMODE == 2) {
    __syncthreads();
    constexpr int PR = (64 / W) / 2, PC = W / 2, CNT = PR * PC * OC;
    const int r0 = hw0 / W;
    float* out = (float*)outv;
    for (int e2 = tid; e2 < CNT; e2 += 256) {
      int oc = e2 % OC, q = e2 / OC, pc = q % PC, pr = q / PC;
      int base = ((2*pr)*W + 2*pc)*OCS + oc;
      float a0 = s_out[base],         a1 = s_out[base + OCS];
      float a2 = s_out[base + W*OCS], a3 = s_out[base + W*OCS + OCS];
      float m = fmaxf(fmaxf(a0, a1), fmaxf(a2, a3));
      out[(((size_t)b*OC + oc)*(H/2) + (r0 >> 1) + pr)*(W/2) + pc] = m;
    }
  }
}

// ---------------------------------------------------------------------------
// Small VALU conv (proven): conv5 / conv6 (4x4 spatial).
// ---------------------------------------------------------------------------
template<int IC, int OC, int OCW, int H, int W, bool HASBN, bool RELU, int POOL>
__global__ __launch_bounds__(256) void k_conv(
    const float* __restrict__ in, const float* __restrict__ w,
    const float* __restrict__ bias,
    const float* __restrict__ bng, const float* __restrict__ bnb,
    const float* __restrict__ bnm, const float* __restrict__ bnv,
    float* __restrict__ out) {
  constexpr int HW    = H * W;
  constexpr int TPIX  = (HW < 64) ? HW : 64;
  constexpr int TILES = HW / TPIX;
  constexpr int NGRP  = 256 / TPIX;
  constexpr int OCA   = OCW / NGRP;
  constexpr int RT    = TPIX / W;
  constexpr int WP    = W + 2;
  constexpr int CH    = 4;
  constexpr int RROWS = RT + 2;
  constexpr int SIN   = CH * RROWS * WP;
  __shared__ float s_in[SIN];
  __shared__ __align__(16) float s_w[CH * 9 * OCW];
  const int tid = threadIdx.x;
  const int b   = blockIdx.x / TILES;
  const int r0  = (blockIdx.x % TILES) * RT;
  const int pix = tid % TPIX;
  const int ocg = tid / TPIX;
  const int r = pix / W, c = pix % W;
  float acc[OCA];
#pragma unroll
  for (int o = 0; o < OCA; ++o) acc[o] = 0.f;
  for (int cc = 0; cc < IC; cc += CH) {
    __syncthreads();
    for (int i = tid; i < SIN; i += 256) {
      int ci  = i / (RROWS * WP);
      int rem = i % (RROWS * WP);
      int rr  = rem / WP + r0 - 1;
      int cw  = rem % WP - 1;
      bool ok = (rr >= 0) && (rr < H) && (cw >= 0) && (cw < W);
      s_in[i] = ok ? in[(((size_t)b*IC + cc + ci)*H + rr)*W + cw] : 0.f;
    }
    for (int i = tid; i < CH * 9 * OCW; i += 256) {
      int oc = i % OCW, k = i / OCW;
      s_w[i] = (oc < OC) ? w[((size_t)oc*IC + cc + (k/9))*9 + (k%9)] : 0.f;
    }
    __syncthreads();
#pragma unroll
    for (int ci = 0; ci < CH; ++ci) {
      const float* sp = s_in + ci*RROWS*WP + r*WP + c;
#pragma unroll
      for (int n = 0; n < 9; ++n) {
        float v = sp[(n/3)*WP + (n%3)];
        const float4* w4 = (const float4*)(s_w + (ci*9 + n)*OCW + ocg*OCA);
#pragma unroll
        for (int o = 0; o < OCA/4; ++o) {
          float4 ww = w4[o];
          acc[4*o  ] = fmaf(v, ww.x, acc[4*o  ]);
          acc[4*o+1] = fmaf(v, ww.y, acc[4*o+1]);
          acc[4*o+2] = fmaf(v, ww.z, acc[4*o+2]);
          acc[4*o+3] = fmaf(v, ww.w, acc[4*o+3]);
        }
      }
    }
  }
#pragma unroll
  for (int o = 0; o < OCA; ++o) {
    int oc = ocg*OCA + o;
    float e = 0.f;
    if (oc < OC) {
      e = acc[o] + bias[oc];
      if constexpr (HASBN) {
        float sc = bng[oc] * rsqrtf(bnv[oc] + 1e-5f);
        e = e * sc + (bnb[oc] - bnm[oc]*sc);
      }
      if constexpr (RELU) e = fmaxf(e, 0.f);
    }
    if constexpr (POOL == 0) {
      if (oc < OC)
        out[(((size_t)b*OC + oc)*H + (r0 + r))*W + c] = e;
    } else {
      float e1 = __shfl_xor(e, 1);
      float e2 = __shfl_xor(e, W);
      float e3 = __shfl_xor(e, W + 1);
      float m = (POOL == 1) ? fmaxf(fmaxf(e, e1), fmaxf(e2, e3))
                            : (e + e1 + e2 + e3) * 0.25f;
      if (oc < OC && !(r & 1) && !(c & 1))
        out[(((size_t)b*OC + oc)*(H/2) + (r0 + r)/2)*(W/2) + (c/2)] = m;
    }
  }
}

__global__ __launch_bounds__(128) void k_fc(const float* __restrict__ in,
                                            const float* __restrict__ w,
                                            const float* __restrict__ bias,
                                            float* __restrict__ out) {
  int j = blockIdx.x, b = threadIdx.x;
  const float4* ib = (const float4*)(in + (size_t)b*512);
  const float4* wb = (const float4*)(w + (size_t)j*512);
  float acc = bias[j];
  for (int k = 0; k < 128; ++k) {
    float4 a = ib[k], q = wb[k];
    acc = fmaf(a.x, q.x, fmaf(a.y, q.y, fmaf(a.z, q.z, fmaf(a.w, q.w, acc))));
  }
  out[(size_t)b*200 + j] = acc;
}

__global__ __launch_bounds__(128) void k_fc1(const float* __restrict__ in,
                                             const float* __restrict__ w,
                                             const float* __restrict__ bias,
                                             float* __restrict__ out) {
  int j = blockIdx.x, b = threadIdx.x;
  const float4* ib = (const float4*)(in + (size_t)b*200);
  const float4* wb = (const float4*)(w + (size_t)j*200);
  float acc = bias[j];
  for (int k = 0; k < 50; ++k) {
    float4 a = ib[k], q = wb[k];
    acc = fmaf(a.x, q.x, fmaf(a.y, q.y, fmaf(a.z, q.z, fmaf(a.w, q.w, acc))));
  }
  out[(size_t)b*16 + j] = acc;
}

// ---------------------------------------------------------------------------
extern "C" void kernel_launch(void* const* d_in, const int* in_sizes, int n_in,
                              void* d_out, int out_size, void* d_ws, size_t ws_size,
                              hipStream_t stream) {
  const float* X    = (const float*)d_in[0];
  const float* D1PW = (const float*)d_in[1];
  const float* D1PB = (const float*)d_in[2];
  const float* D1W  = (const float*)d_in[3];
  const float* BN1G = (const float*)d_in[4];
  const float* BN1B = (const float*)d_in[5];
  const float* BN1M = (const float*)d_in[6];
  const float* BN1V = (const float*)d_in[7];
  const float* C2W  = (const float*)d_in[8];
  const float* C2B  = (const float*)d_in[9];
  const float* BN2G = (const float*)d_in[10];
  const float* BN2B = (const float*)d_in[11];
  const float* BN2M = (const float*)d_in[12];
  const float* BN2V = (const float*)d_in[13];
  const float* D3PW = (const float*)d_in[14];
  const float* D3PB = (const float*)d_in[15];
  const float* D3W  = (const float*)d_in[16];
  const float* BN3G = (const float*)d_in[17];
  const float* BN3B = (const float*)d_in[18];
  const float* BN3M = (const float*)d_in[19];
  const float* BN3V = (const float*)d_in[20];
  const float* C4W  = (const float*)d_in[21];
  const float* C4B  = (const float*)d_in[22];
  const float* BN4G = (const float*)d_in[23];
  const float* BN4B = (const float*)d_in[24];
  const float* BN4M = (const float*)d_in[25];
  const float* BN4V = (const float*)d_in[26];
  const float* C5W  = (const float*)d_in[27];
  const float* C5B  = (const float*)d_in[28];
  const float* BN5G = (const float*)d_in[29];
  const float* BN5B = (const float*)d_in[30];
  const float* BN5M = (const float*)d_in[31];
  const float* BN5V = (const float*)d_in[32];
  const float* C6W  = (const float*)d_in[33];
  const float* C6B  = (const float*)d_in[34];
  const float* BN6G = (const float*)d_in[35];
  const float* BN6B = (const float*)d_in[36];
  const float* BN6M = (const float*)d_in[37];
  const float* BN6V = (const float*)d_in[38];
  const float* FCW  = (const float*)d_in[39];
  const float* FCB  = (const float*)d_in[40];
  const float* FC1W = (const float*)d_in[41];
  const float* FC1B = (const float*)d_in[42];

  char* ws = (char*)d_ws;
  unsigned short* pk_d1pw = (unsigned short*)(ws + PK_D1PW);
  unsigned short* pk_d1w  = (unsigned short*)(ws + PK_D1W);
  unsigned short* pk_c2w  = (unsigned short*)(ws + PK_C2W);
  unsigned short* pk_d3pw = (unsigned short*)(ws + PK_D3PW);
  unsigned short* pk_d3w  = (unsigned short*)(ws + PK_D3W);
  unsigned short* pk_c4w  = (unsigned short*)(ws + PK_C4W);
  unsigned short* off1 = (unsigned short*)(ws + OFF1_B);
  unsigned short* off3 = (unsigned short*)(ws + OFF3_B);
  float* h1   = (float*)(ws + H1_B);
  float* h2p  = (float*)(ws + H2P_B);
  float* h3   = (float*)(ws + H3_B);
  float* h4p  = (float*)(ws + H4P_B);
  float* h5   = (float*)(ws + H5_B);
  float* h6p  = (float*)(ws + H6P_B);
  float* fco  = (float*)(ws + FCO_B);
  float* outp = (float*)d_out;

  // weight pre-pack (bf16 hi/lo planes, zero-padded)
  k_pack<<<232, 256, 0, stream>>>(D1PW, pk_d1pw,  18, 1800,  32, 1856);
  k_pack<<<696, 256, 0, stream>>>(D1W,  pk_d1w,   96, 1800,  96, 1856);
  k_pack<<<336, 256, 0, stream>>>(C2W,  pk_c2w,   96,  864,  96,  896);
  k_pack<<<112, 256, 0, stream>>>(D3PW, pk_d3pw,  18,  864,  32,  896);
  k_pack<<<392, 256, 0, stream>>>(D3W,  pk_d3w,  108,  864, 112,  896);
  k_pack<<<448, 256, 0, stream>>>(C4W,  pk_c4w,  108,  972, 112, 1024);

  // block 1: offset conv -> deform einsum + BN + ReLU
  k_gemm<false,200,18,32,2,16,16,true,false,false,1><<<512, 256, 0, stream>>>(
      X, nullptr, pk_d1pw, D1PB, nullptr, nullptr, nullptr, nullptr, off1);
  k_gemm<true,200,96,96,6,16,16,false,true,true,0><<<512, 256, 0, stream>>>(
      X, off1, pk_d1w, nullptr, BN1G, BN1B, BN1M, BN1V, h1);
  // block 2: conv + bias + BN + ReLU + maxpool
  k_gemm<false,96,96,96,6,16,16,true,true,true,2><<<512, 256, 0, stream>>>(
      h1, nullptr, pk_c2w, C2B, BN2G, BN2B, BN2M, BN2V, h2p);
  // block 3: offset conv -> deform einsum + BN + ReLU
  k_gemm<false,96,18,32,2,8,8,true,false,false,1><<<128, 256, 0, stream>>>(
      h2p, nullptr, pk_d3pw, D3PB, nullptr, nullptr, nullptr, nullptr, off3);
  k_gemm<true,96,108,112,7,8,8,false,true,true,0><<<128, 256, 0, stream>>>(
      h2p, off3, pk_d3w, nullptr, BN3G, BN3B, BN3M, BN3V, h3);
  // block 4: conv + bias + BN + ReLU + maxpool
  k_gemm<false,108,108,112,7,8,8,true,true,true,2><<<128, 256, 0, stream>>>(
      h3, nullptr, pk_c4w, C4B, BN4G, BN4B, BN4M, BN4V, h4p);
  // block 5: conv + BN + ReLU (VALU)
  k_conv<108,128,128,4,4,true,true,0><<<128, 256, 0, stream>>>(
      h4p, C5W, C5B, BN5G, BN5B, BN5M, BN5V, h5);
  // block 6: conv + BN + ReLU + avgpool (VALU, ReLU before avg)
  k_conv<128,128,128,4,4,true,true,2><<<128, 256, 0, stream>>>(
      h5, C6W, C6B, BN6G, BN6B, BN6M, BN6V, h6p);
  // classifier
  k_fc<<<200, 128, 0, stream>>>(h6p, FCW, FCB, fco);
  k_fc1<<<16, 128, 0, stream>>>(fco, FC1W, FC1B, outp);
}